// Round 9
// baseline (336.905 us; speedup 1.0000x reference)
//
#include <hip/hip_runtime.h>
#include <hip/hip_fp16.h>
#include <math.h>

// ---------------------------------------------------------------------------
// GCN 3-layer. Per layer: P = X@W via split-fp16 MFMA (fp32-grade accuracy),
// epilogue stores P' = dis_r*P_r as fp16. agg: out[d] = dis_d*(sum P'[src] +
// P'[d]) + b. agg gathers TWO rows per VMEM instruction (lane halves), since
// the gather path measured request-rate-bound, not byte-bound.
// ---------------------------------------------------------------------------

typedef _Float16 half8 __attribute__((ext_vector_type(8)));
typedef float f32x4 __attribute__((ext_vector_type(4)));

__global__ void count_kernel(const int* __restrict__ dst, int* __restrict__ counts, int E) {
    int i = blockIdx.x * blockDim.x + threadIdx.x;
    int st = gridDim.x * blockDim.x;
    for (; i < E; i += st) atomicAdd(&counts[dst[i]], 1);
}

// --------------------------- multi-block scan ------------------------------
__global__ __launch_bounds__(256) void block_sum_kernel(const int* __restrict__ counts,
                                                        int* __restrict__ bsum, int n) {
    const int b = blockIdx.x;
    const int t = threadIdx.x;
    const int idx = b * 256 + t;
    int v = (idx < n) ? counts[idx] : 0;
#pragma unroll
    for (int o = 32; o > 0; o >>= 1) v += __shfl_down(v, o, 64);
    __shared__ int ws[4];
    if ((t & 63) == 0) ws[t >> 6] = v;
    __syncthreads();
    if (t == 0) bsum[b] = ws[0] + ws[1] + ws[2] + ws[3];
}

__global__ __launch_bounds__(256) void small_scan_kernel(int* __restrict__ bsum, int nb) {
    __shared__ int sm[256];
    const int t = threadIdx.x;
    int v = (t < nb) ? bsum[t] : 0;
    sm[t] = v;
    __syncthreads();
    for (int o = 1; o < 256; o <<= 1) {
        int x = (t >= o) ? sm[t - o] : 0;
        __syncthreads();
        sm[t] += x;
        __syncthreads();
    }
    if (t < nb) bsum[t] = sm[t] - v;   // exclusive
}

// scan within block + write dis (fused)
__global__ __launch_bounds__(256) void scan_block_kernel(const int* __restrict__ counts,
                                                         const int* __restrict__ bsum,
                                                         int* __restrict__ offs,
                                                         float* __restrict__ dis,
                                                         int n, int E) {
    const int b = blockIdx.x;
    const int t = threadIdx.x;
    const int idx = b * 256 + t;
    int v = (idx < n) ? counts[idx] : 0;
    if (idx < n) dis[idx] = rsqrtf((float)(v + 1));   // +1 self-loop
    __shared__ int sm[256];
    sm[t] = v;
    __syncthreads();
    for (int o = 1; o < 256; o <<= 1) {
        int x = (t >= o) ? sm[t - o] : 0;
        __syncthreads();
        sm[t] += x;
        __syncthreads();
    }
    if (idx < n) offs[idx] = bsum[b] + sm[t] - v;   // exclusive prefix
    if (idx == n) offs[n] = E;
}

// csr entry = src index only; position via atomic cursor (init = copy of offs)
__global__ void fill_kernel(const int* __restrict__ src, const int* __restrict__ dst,
                            int* __restrict__ cursor, int* __restrict__ csr_s, int E) {
    int i = blockIdx.x * blockDim.x + threadIdx.x;
    int st = gridDim.x * blockDim.x;
    for (; i < E; i += st) {
        int p = atomicAdd(&cursor[dst[i]], 1);
        csr_s[p] = src[i];
    }
}

// W1,W2 (128x128), W3 (128x64) -> transposed WT[c][k] hi/lo fp16.
__global__ __launch_bounds__(256) void wsplit_kernel(const float* __restrict__ W1,
                                                     const float* __restrict__ W2,
                                                     const float* __restrict__ W3,
                                                     _Float16* __restrict__ hi,
                                                     _Float16* __restrict__ lo) {
    int idx = blockIdx.x * 256 + threadIdx.x;
    if (idx >= 40960) return;
    float v;
    if (idx < 16384) {
        int c = idx >> 7, k = idx & 127;
        v = W1[k * 128 + c];
    } else if (idx < 32768) {
        int j = idx - 16384;
        int c = j >> 7, k = j & 127;
        v = W2[k * 128 + c];
    } else {
        int j = idx - 32768;
        int c = j >> 7, k = j & 127;
        v = W3[k * 64 + c];
    }
    _Float16 h = (_Float16)v;
    hi[idx] = h;
    lo[idx] = (_Float16)(v - (float)h);
}

// ---------------------------------------------------------------------------
// MFMA GEMM cores. Fragment maps (16x16x32): A: row=l&15, k=8*(l>>4)+j.
// B: col=l&15, k=8*(l>>4)+j. C/D: col=l&15, row=(l>>4)*4+reg.
// 4 waves/block, 32 rows/wave. WT[c][k] => contiguous 16B B-fragments.
// ---------------------------------------------------------------------------
template <int NOUT>
__device__ __forceinline__ void gemm_core(const half8* __restrict__ XhiV,
                                          const half8* __restrict__ XloV,
                                          const _Float16* __restrict__ WThi,
                                          const _Float16* __restrict__ WTlo,
                                          const float* __restrict__ dis,
                                          _Float16* __restrict__ Y, int nrows,
                                          bool from_f32, const float4* X4) {
    constexpr int CT = NOUT / 16;
    const int wave = threadIdx.x >> 6;
    const int lane = threadIdx.x & 63;
    const int lrow = lane & 15;
    const int lk = lane >> 4;
    const int r0 = (blockIdx.x * 4 + wave) * 32;

    const f32x4 Z = {0.f, 0.f, 0.f, 0.f};
    f32x4 acc[2][CT];
#pragma unroll
    for (int a = 0; a < 2; ++a)
#pragma unroll
        for (int b = 0; b < CT; ++b) acc[a][b] = Z;

    const half8* WhiV = (const half8*)WThi;
    const half8* WloV = (const half8*)WTlo;

    int ar0 = r0 + lrow;
    int ar1 = r0 + 16 + lrow;
    if (ar0 > nrows - 1) ar0 = nrows - 1;
    if (ar1 > nrows - 1) ar1 = nrows - 1;

#pragma unroll
    for (int ks = 0; ks < 4; ++ks) {
        const int kidx = ks * 4 + lk;
        half8 a0h, a0l, a1h, a1l;
        if (from_f32) {
            float4 u0 = X4[(size_t)ar0 * 32 + 2 * kidx];
            float4 u1 = X4[(size_t)ar0 * 32 + 2 * kidx + 1];
            float4 w0 = X4[(size_t)ar1 * 32 + 2 * kidx];
            float4 w1 = X4[(size_t)ar1 * 32 + 2 * kidx + 1];
            float v0[8] = {u0.x, u0.y, u0.z, u0.w, u1.x, u1.y, u1.z, u1.w};
            float v1[8] = {w0.x, w0.y, w0.z, w0.w, w1.x, w1.y, w1.z, w1.w};
#pragma unroll
            for (int j = 0; j < 8; ++j) {
                _Float16 hh = (_Float16)v0[j];
                a0h[j] = hh;
                a0l[j] = (_Float16)(v0[j] - (float)hh);
                _Float16 gg = (_Float16)v1[j];
                a1h[j] = gg;
                a1l[j] = (_Float16)(v1[j] - (float)gg);
            }
        } else {
            a0h = XhiV[(size_t)ar0 * 16 + kidx];
            a0l = XloV[(size_t)ar0 * 16 + kidx];
            a1h = XhiV[(size_t)ar1 * 16 + kidx];
            a1l = XloV[(size_t)ar1 * 16 + kidx];
        }
#pragma unroll
        for (int ct = 0; ct < CT; ++ct) {
            const size_t bidx = (size_t)(ct * 16 + lrow) * 16 + kidx;
            half8 bh = WhiV[bidx];
            half8 bl = WloV[bidx];
            acc[0][ct] = __builtin_amdgcn_mfma_f32_16x16x32_f16(a0l, bh, acc[0][ct], 0, 0, 0);
            acc[0][ct] = __builtin_amdgcn_mfma_f32_16x16x32_f16(a0h, bl, acc[0][ct], 0, 0, 0);
            acc[0][ct] = __builtin_amdgcn_mfma_f32_16x16x32_f16(a0h, bh, acc[0][ct], 0, 0, 0);
            acc[1][ct] = __builtin_amdgcn_mfma_f32_16x16x32_f16(a1l, bh, acc[1][ct], 0, 0, 0);
            acc[1][ct] = __builtin_amdgcn_mfma_f32_16x16x32_f16(a1h, bl, acc[1][ct], 0, 0, 0);
            acc[1][ct] = __builtin_amdgcn_mfma_f32_16x16x32_f16(a1h, bh, acc[1][ct], 0, 0, 0);
        }
    }

    const int orow = r0 + lk * 4;
#pragma unroll
    for (int rt = 0; rt < 2; ++rt) {
#pragma unroll
        for (int r = 0; r < 4; ++r) {
            int row = orow + rt * 16 + r;
            if (row < nrows) {
                float dd = dis[row];
#pragma unroll
                for (int ct = 0; ct < CT; ++ct) {
                    Y[(size_t)row * NOUT + ct * 16 + lrow] =
                        (_Float16)(dd * acc[rt][ct][r]);
                }
            }
        }
    }
}

template <int NOUT>
__global__ __launch_bounds__(256) void gemm_mfma(const _Float16* __restrict__ Xhi,
                                                 const _Float16* __restrict__ Xlo,
                                                 const _Float16* __restrict__ WThi,
                                                 const _Float16* __restrict__ WTlo,
                                                 const float* __restrict__ dis,
                                                 _Float16* __restrict__ Y, int nrows) {
    gemm_core<NOUT>((const half8*)Xhi, (const half8*)Xlo, WThi, WTlo, dis, Y, nrows,
                    false, nullptr);
}

// layer-1 variant: reads fp32 X directly, splits in-register (kills xsplit pass)
__global__ __launch_bounds__(256) void gemm_mfma_l1(const float* __restrict__ X,
                                                    const _Float16* __restrict__ WThi,
                                                    const _Float16* __restrict__ WTlo,
                                                    const float* __restrict__ dis,
                                                    _Float16* __restrict__ Y, int nrows) {
    gemm_core<128>(nullptr, nullptr, WThi, WTlo, dis, Y, nrows, true,
                   (const float4*)X);
}

// ---------------------------------------------------------------------------
// Aggregation: ONE WAVE per node, 4 nodes per block. TWO rows per gather
// instruction: lanes 0..31 read edge 2p, lanes 32..63 read edge 2p+1
// (8B/lane for F=128 -> feats 4li..4li+3; 4B/lane for F=64 -> feats 2li,2li+1).
// shfl_xor(32) combines halves once per node. fp32 accumulate.
// ---------------------------------------------------------------------------
template <int F, bool RELU, bool SPLIT>
__global__ __launch_bounds__(256) void agg_kernel(const __half* __restrict__ h,
                                                  const float* __restrict__ dis,
                                                  const int* __restrict__ offs,
                                                  const int* __restrict__ csr_s,
                                                  const float* __restrict__ bias,
                                                  float* __restrict__ outf,
                                                  __half* __restrict__ ohi,
                                                  __half* __restrict__ olo, int n) {
    const int d = blockIdx.x * 4 + (threadIdx.x >> 6);
    if (d >= n) return;
    const int lane = threadIdx.x & 63;
    const int li = lane & 31;
    const bool upper = lane >= 32;
    const int beg = offs[d];
    const int end = offs[d + 1];

    if constexpr (F == 128) {
        const uint2* hv = (const uint2*)h;   // 32 uint2 per row
        float a0 = 0.f, a1 = 0.f, a2 = 0.f, a3 = 0.f;
        int i = beg;
        for (; i + 16 <= end; i += 16) {     // 8 pairs in flight
            int s[16];
#pragma unroll
            for (int j = 0; j < 16; ++j) s[j] = csr_s[i + j];
            uint2 v[8];
#pragma unroll
            for (int p = 0; p < 8; ++p) {
                int row = upper ? s[2 * p + 1] : s[2 * p];
                v[p] = hv[(size_t)row * 32 + li];
            }
#pragma unroll
            for (int p = 0; p < 8; ++p) {
                float2 f0 = __half22float2(*reinterpret_cast<__half2*>(&v[p].x));
                float2 f1 = __half22float2(*reinterpret_cast<__half2*>(&v[p].y));
                a0 += f0.x; a1 += f0.y; a2 += f1.x; a3 += f1.y;
            }
        }
        if (i + 8 <= end) {                  // 4 pairs
            int s[8];
#pragma unroll
            for (int j = 0; j < 8; ++j) s[j] = csr_s[i + j];
            uint2 v[4];
#pragma unroll
            for (int p = 0; p < 4; ++p) {
                int row = upper ? s[2 * p + 1] : s[2 * p];
                v[p] = hv[(size_t)row * 32 + li];
            }
#pragma unroll
            for (int p = 0; p < 4; ++p) {
                float2 f0 = __half22float2(*reinterpret_cast<__half2*>(&v[p].x));
                float2 f1 = __half22float2(*reinterpret_cast<__half2*>(&v[p].y));
                a0 += f0.x; a1 += f0.y; a2 += f1.x; a3 += f1.y;
            }
            i += 8;
        }
        for (; i + 2 <= end; i += 2) {       // single pairs
            int s0 = csr_s[i], s1 = csr_s[i + 1];
            int row = upper ? s1 : s0;
            uint2 v = hv[(size_t)row * 32 + li];
            float2 f0 = __half22float2(*reinterpret_cast<__half2*>(&v.x));
            float2 f1 = __half22float2(*reinterpret_cast<__half2*>(&v.y));
            a0 += f0.x; a1 += f0.y; a2 += f1.x; a3 += f1.y;
        }
        if (!upper) {
            if (i < end) {                   // odd tail edge
                uint2 v = hv[(size_t)csr_s[i] * 32 + li];
                float2 f0 = __half22float2(*reinterpret_cast<__half2*>(&v.x));
                float2 f1 = __half22float2(*reinterpret_cast<__half2*>(&v.y));
                a0 += f0.x; a1 += f0.y; a2 += f1.x; a3 += f1.y;
            }
            {                                // self row
                uint2 v = hv[(size_t)d * 32 + li];
                float2 f0 = __half22float2(*reinterpret_cast<__half2*>(&v.x));
                float2 f1 = __half22float2(*reinterpret_cast<__half2*>(&v.y));
                a0 += f0.x; a1 += f0.y; a2 += f1.x; a3 += f1.y;
            }
        }
        a0 += __shfl_xor(a0, 32);
        a1 += __shfl_xor(a1, 32);
        a2 += __shfl_xor(a2, 32);
        a3 += __shfl_xor(a3, 32);
        if (!upper) {
            float dd = dis[d];
            float4 b4 = ((const float4*)bias)[li];
            float r0 = fmaf(dd, a0, b4.x);
            float r1 = fmaf(dd, a1, b4.y);
            float r2 = fmaf(dd, a2, b4.z);
            float r3 = fmaf(dd, a3, b4.w);
            if (RELU) {
                r0 = fmaxf(r0, 0.f); r1 = fmaxf(r1, 0.f);
                r2 = fmaxf(r2, 0.f); r3 = fmaxf(r3, 0.f);
            }
            if constexpr (SPLIT) {
                __half h0 = __float2half(r0), h1 = __float2half(r1);
                __half h2 = __float2half(r2), h3 = __float2half(r3);
                __half2 hh01 = __halves2half2(h0, h1), hh23 = __halves2half2(h2, h3);
                uint2 uh;
                uh.x = *reinterpret_cast<unsigned*>(&hh01);
                uh.y = *reinterpret_cast<unsigned*>(&hh23);
                ((uint2*)ohi)[(size_t)d * 32 + li] = uh;
                __half l0 = __float2half(r0 - __half2float(h0));
                __half l1 = __float2half(r1 - __half2float(h1));
                __half l2 = __float2half(r2 - __half2float(h2));
                __half l3 = __float2half(r3 - __half2float(h3));
                __half2 ll01 = __halves2half2(l0, l1), ll23 = __halves2half2(l2, l3);
                uint2 ul;
                ul.x = *reinterpret_cast<unsigned*>(&ll01);
                ul.y = *reinterpret_cast<unsigned*>(&ll23);
                ((uint2*)olo)[(size_t)d * 32 + li] = ul;
            } else {
                ((float4*)outf)[(size_t)d * 32 + li] = make_float4(r0, r1, r2, r3);
            }
        }
    } else {   // F == 64
        const unsigned* hv = (const unsigned*)h;   // 32 uints per row
        float a0 = 0.f, a1 = 0.f;
        int i = beg;
        for (; i + 16 <= end; i += 16) {
            int s[16];
#pragma unroll
            for (int j = 0; j < 16; ++j) s[j] = csr_s[i + j];
            unsigned v[8];
#pragma unroll
            for (int p = 0; p < 8; ++p) {
                int row = upper ? s[2 * p + 1] : s[2 * p];
                v[p] = hv[(size_t)row * 32 + li];
            }
#pragma unroll
            for (int p = 0; p < 8; ++p) {
                float2 f = __half22float2(*reinterpret_cast<__half2*>(&v[p]));
                a0 += f.x; a1 += f.y;
            }
        }
        if (i + 8 <= end) {
            int s[8];
#pragma unroll
            for (int j = 0; j < 8; ++j) s[j] = csr_s[i + j];
            unsigned v[4];
#pragma unroll
            for (int p = 0; p < 4; ++p) {
                int row = upper ? s[2 * p + 1] : s[2 * p];
                v[p] = hv[(size_t)row * 32 + li];
            }
#pragma unroll
            for (int p = 0; p < 4; ++p) {
                float2 f = __half22float2(*reinterpret_cast<__half2*>(&v[p]));
                a0 += f.x; a1 += f.y;
            }
            i += 8;
        }
        for (; i + 2 <= end; i += 2) {
            int s0 = csr_s[i], s1 = csr_s[i + 1];
            int row = upper ? s1 : s0;
            unsigned v = hv[(size_t)row * 32 + li];
            float2 f = __half22float2(*reinterpret_cast<__half2*>(&v));
            a0 += f.x; a1 += f.y;
        }
        if (!upper) {
            if (i < end) {
                unsigned v = hv[(size_t)csr_s[i] * 32 + li];
                float2 f = __half22float2(*reinterpret_cast<__half2*>(&v));
                a0 += f.x; a1 += f.y;
            }
            {
                unsigned v = hv[(size_t)d * 32 + li];
                float2 f = __half22float2(*reinterpret_cast<__half2*>(&v));
                a0 += f.x; a1 += f.y;
            }
        }
        a0 += __shfl_xor(a0, 32);
        a1 += __shfl_xor(a1, 32);
        if (!upper) {
            float dd = dis[d];
            float2 b2 = ((const float2*)bias)[li];
            float r0 = fmaf(dd, a0, b2.x);
            float r1 = fmaf(dd, a1, b2.y);
            if (RELU) {
                r0 = fmaxf(r0, 0.f);
                r1 = fmaxf(r1, 0.f);
            }
            ((float2*)outf)[(size_t)d * 32 + li] = make_float2(r0, r1);
        }
    }
}

// ---------------------------------------------------------------------------

extern "C" void kernel_launch(void* const* d_in, const int* in_sizes, int n_in,
                              void* d_out, int out_size, void* d_ws, size_t ws_size,
                              hipStream_t stream) {
    const float* x  = (const float*)d_in[0];
    const int*   ei = (const int*)d_in[1];
    const float* W1 = (const float*)d_in[2];
    const float* b1 = (const float*)d_in[3];
    const float* W2 = (const float*)d_in[4];
    const float* b2 = (const float*)d_in[5];
    const float* W3 = (const float*)d_in[6];
    const float* b3 = (const float*)d_in[7];

    const int N = in_sizes[0] / 128;
    const int E = in_sizes[1] / 2;
    const int* src = ei;
    const int* dst = ei + E;
    float* out = (float*)d_out;

    char* w = (char*)d_ws;
    auto take = [&](size_t bytes) -> void* {
        void* p = (void*)w;
        w += (bytes + 255) & ~(size_t)255;
        return p;
    };
    int*      counts = (int*)take((size_t)N * 4);
    int*      offs   = (int*)take((size_t)(N + 1) * 4);
    int*      cursor = (int*)take((size_t)N * 4);
    float*    dis    = (float*)take((size_t)N * 4);
    int*      bsum   = (int*)take((size_t)1024 * 4);
    int*      csr_s  = (int*)take((size_t)E * 4);
    _Float16* G16    = (_Float16*)take((size_t)N * 128 * 2);  // prescaled fp16 rows
    _Float16* Xhi    = (_Float16*)take((size_t)N * 128 * 2);  // GEMM input hi
    _Float16* Xlo    = (_Float16*)take((size_t)N * 128 * 2);  // GEMM input lo
    _Float16* Whi    = (_Float16*)take((size_t)40960 * 2);
    _Float16* Wlo    = (_Float16*)take((size_t)40960 * 2);

    const int NBLK = (N + 256) / 256;

    // --- graph preprocessing ---
    hipMemsetAsync(counts, 0, (size_t)N * 4, stream);
    count_kernel<<<2048, 256, 0, stream>>>(dst, counts, E);
    block_sum_kernel<<<NBLK, 256, 0, stream>>>(counts, bsum, N);
    small_scan_kernel<<<1, 256, 0, stream>>>(bsum, NBLK);
    scan_block_kernel<<<NBLK, 256, 0, stream>>>(counts, bsum, offs, dis, N, E);
    hipMemcpyAsync(cursor, offs, (size_t)N * 4, hipMemcpyDeviceToDevice, stream);
    fill_kernel<<<2048, 256, 0, stream>>>(src, dst, cursor, csr_s, E);

    // --- weight split (160 KB, trivial) ---
    wsplit_kernel<<<160, 256, 0, stream>>>(W1, W2, W3, Whi, Wlo);

    const int gblocks = (N + 127) / 128;   // 128 rows per block (4 waves x 32)
    const int ablocks = (N + 3) / 4;

    // layer 1 (fp32 X split in-register)
    gemm_mfma_l1<<<gblocks, 256, 0, stream>>>(x, Whi, Wlo, dis, G16, N);
    agg_kernel<128, true, true><<<ablocks, 256, 0, stream>>>(
        (const __half*)G16, dis, offs, csr_s, b1, nullptr, (__half*)Xhi, (__half*)Xlo, N);
    // layer 2
    gemm_mfma<128><<<gblocks, 256, 0, stream>>>(Xhi, Xlo, Whi + 16384, Wlo + 16384,
                                                dis, G16, N);
    agg_kernel<128, true, true><<<ablocks, 256, 0, stream>>>(
        (const __half*)G16, dis, offs, csr_s, b2, nullptr, (__half*)Xhi, (__half*)Xlo, N);
    // layer 3
    gemm_mfma<64><<<gblocks, 256, 0, stream>>>(Xhi, Xlo, Whi + 32768, Wlo + 32768,
                                               dis, G16, N);
    agg_kernel<64, false, false><<<ablocks, 256, 0, stream>>>(
        (const __half*)G16, dis, offs, csr_s, b3, out, nullptr, nullptr, N);
}

// Round 10
// 247.986 us; speedup vs baseline: 1.3586x; 1.3586x over previous
//
#include <hip/hip_runtime.h>
#include <hip/hip_fp16.h>
#include <math.h>

// ---------------------------------------------------------------------------
// GCN 3-layer. Per layer: P = X@W via split-fp16 MFMA (fp32-grade accuracy),
// epilogue stores P' = dis_r*P_r as fp16. agg: out[d] = dis_d*(sum P'[src] +
// P'[d]) + b. agg gathers TWO rows per VMEM instruction (lane halves).
// NOTE: agg uses ONLY named scalars (no per-thread arrays) -- LLVM's
// PromoteAlloca demoted int s[16] to LDS in R9 (LDS=16KB, 9M bank conflicts).
// ---------------------------------------------------------------------------

typedef _Float16 half8 __attribute__((ext_vector_type(8)));
typedef float f32x4 __attribute__((ext_vector_type(4)));

// counts in-degree AND records each edge's rank within its dst bucket
__global__ void count_kernel(const int* __restrict__ dst, int* __restrict__ counts,
                             int* __restrict__ rank, int E) {
    int i = blockIdx.x * blockDim.x + threadIdx.x;
    int st = gridDim.x * blockDim.x;
    for (; i < E; i += st) rank[i] = atomicAdd(&counts[dst[i]], 1);
}

// --------------------------- multi-block scan ------------------------------
__global__ __launch_bounds__(256) void block_sum_kernel(const int* __restrict__ counts,
                                                        int* __restrict__ bsum, int n) {
    const int b = blockIdx.x;
    const int t = threadIdx.x;
    const int idx = b * 256 + t;
    int v = (idx < n) ? counts[idx] : 0;
#pragma unroll
    for (int o = 32; o > 0; o >>= 1) v += __shfl_down(v, o, 64);
    __shared__ int ws[4];
    if ((t & 63) == 0) ws[t >> 6] = v;
    __syncthreads();
    if (t == 0) bsum[b] = ws[0] + ws[1] + ws[2] + ws[3];
}

__global__ __launch_bounds__(256) void small_scan_kernel(int* __restrict__ bsum, int nb) {
    __shared__ int sm[256];
    const int t = threadIdx.x;
    int v = (t < nb) ? bsum[t] : 0;
    sm[t] = v;
    __syncthreads();
    for (int o = 1; o < 256; o <<= 1) {
        int x = (t >= o) ? sm[t - o] : 0;
        __syncthreads();
        sm[t] += x;
        __syncthreads();
    }
    if (t < nb) bsum[t] = sm[t] - v;   // exclusive
}

// scan within block + write dis (fused)
__global__ __launch_bounds__(256) void scan_block_kernel(const int* __restrict__ counts,
                                                         const int* __restrict__ bsum,
                                                         int* __restrict__ offs,
                                                         float* __restrict__ dis,
                                                         int n, int E) {
    const int b = blockIdx.x;
    const int t = threadIdx.x;
    const int idx = b * 256 + t;
    int v = (idx < n) ? counts[idx] : 0;
    if (idx < n) dis[idx] = rsqrtf((float)(v + 1));   // +1 self-loop
    __shared__ int sm[256];
    sm[t] = v;
    __syncthreads();
    for (int o = 1; o < 256; o <<= 1) {
        int x = (t >= o) ? sm[t - o] : 0;
        __syncthreads();
        sm[t] += x;
        __syncthreads();
    }
    if (idx < n) offs[idx] = bsum[b] + sm[t] - v;   // exclusive prefix
    if (idx == n) offs[n] = E;
}

__global__ void fill_kernel(const int* __restrict__ src, const int* __restrict__ dst,
                            const int* __restrict__ offs, const int* __restrict__ rank,
                            int* __restrict__ csr_s, int E) {
    int i = blockIdx.x * blockDim.x + threadIdx.x;
    int st = gridDim.x * blockDim.x;
    for (; i < E; i += st) {
        int p = offs[dst[i]] + rank[i];
        csr_s[p] = src[i];
    }
}

// W1,W2 (128x128), W3 (128x64) -> transposed WT[c][k] hi/lo fp16.
__global__ __launch_bounds__(256) void wsplit_kernel(const float* __restrict__ W1,
                                                     const float* __restrict__ W2,
                                                     const float* __restrict__ W3,
                                                     _Float16* __restrict__ hi,
                                                     _Float16* __restrict__ lo) {
    int idx = blockIdx.x * 256 + threadIdx.x;
    if (idx >= 40960) return;
    float v;
    if (idx < 16384) {
        int c = idx >> 7, k = idx & 127;
        v = W1[k * 128 + c];
    } else if (idx < 32768) {
        int j = idx - 16384;
        int c = j >> 7, k = j & 127;
        v = W2[k * 128 + c];
    } else {
        int j = idx - 32768;
        int c = j >> 7, k = j & 127;
        v = W3[k * 64 + c];
    }
    _Float16 h = (_Float16)v;
    hi[idx] = h;
    lo[idx] = (_Float16)(v - (float)h);
}

// ---------------------------------------------------------------------------
// MFMA GEMM cores. Fragment maps (16x16x32): A: row=l&15, k=8*(l>>4)+j.
// B: col=l&15, k=8*(l>>4)+j. C/D: col=l&15, row=(l>>4)*4+reg.
// 4 waves/block, 32 rows/wave. WT[c][k] => contiguous 16B B-fragments.
// ---------------------------------------------------------------------------
template <int NOUT, bool FROM_F32>
__device__ __forceinline__ void gemm_core(const half8* __restrict__ XhiV,
                                          const half8* __restrict__ XloV,
                                          const _Float16* __restrict__ WThi,
                                          const _Float16* __restrict__ WTlo,
                                          const float* __restrict__ dis,
                                          _Float16* __restrict__ Y, int nrows,
                                          const float4* X4) {
    constexpr int CT = NOUT / 16;
    const int wave = threadIdx.x >> 6;
    const int lane = threadIdx.x & 63;
    const int lrow = lane & 15;
    const int lk = lane >> 4;
    const int r0 = (blockIdx.x * 4 + wave) * 32;

    const f32x4 Z = {0.f, 0.f, 0.f, 0.f};
    f32x4 acc[2][CT];
#pragma unroll
    for (int a = 0; a < 2; ++a)
#pragma unroll
        for (int b = 0; b < CT; ++b) acc[a][b] = Z;

    const half8* WhiV = (const half8*)WThi;
    const half8* WloV = (const half8*)WTlo;

    int ar0 = r0 + lrow;
    int ar1 = r0 + 16 + lrow;
    if (ar0 > nrows - 1) ar0 = nrows - 1;
    if (ar1 > nrows - 1) ar1 = nrows - 1;

#pragma unroll
    for (int ks = 0; ks < 4; ++ks) {
        const int kidx = ks * 4 + lk;
        half8 a0h, a0l, a1h, a1l;
        if constexpr (FROM_F32) {
            float4 u0 = X4[(size_t)ar0 * 32 + 2 * kidx];
            float4 u1 = X4[(size_t)ar0 * 32 + 2 * kidx + 1];
            float4 w0 = X4[(size_t)ar1 * 32 + 2 * kidx];
            float4 w1 = X4[(size_t)ar1 * 32 + 2 * kidx + 1];
            float v0[8] = {u0.x, u0.y, u0.z, u0.w, u1.x, u1.y, u1.z, u1.w};
            float v1[8] = {w0.x, w0.y, w0.z, w0.w, w1.x, w1.y, w1.z, w1.w};
#pragma unroll
            for (int j = 0; j < 8; ++j) {
                _Float16 hh = (_Float16)v0[j];
                a0h[j] = hh;
                a0l[j] = (_Float16)(v0[j] - (float)hh);
                _Float16 gg = (_Float16)v1[j];
                a1h[j] = gg;
                a1l[j] = (_Float16)(v1[j] - (float)gg);
            }
        } else {
            a0h = XhiV[(size_t)ar0 * 16 + kidx];
            a0l = XloV[(size_t)ar0 * 16 + kidx];
            a1h = XhiV[(size_t)ar1 * 16 + kidx];
            a1l = XloV[(size_t)ar1 * 16 + kidx];
        }
#pragma unroll
        for (int ct = 0; ct < CT; ++ct) {
            const size_t bidx = (size_t)(ct * 16 + lrow) * 16 + kidx;
            half8 bh = WhiV[bidx];
            half8 bl = WloV[bidx];
            acc[0][ct] = __builtin_amdgcn_mfma_f32_16x16x32_f16(a0l, bh, acc[0][ct], 0, 0, 0);
            acc[0][ct] = __builtin_amdgcn_mfma_f32_16x16x32_f16(a0h, bl, acc[0][ct], 0, 0, 0);
            acc[0][ct] = __builtin_amdgcn_mfma_f32_16x16x32_f16(a0h, bh, acc[0][ct], 0, 0, 0);
            acc[1][ct] = __builtin_amdgcn_mfma_f32_16x16x32_f16(a1l, bh, acc[1][ct], 0, 0, 0);
            acc[1][ct] = __builtin_amdgcn_mfma_f32_16x16x32_f16(a1h, bl, acc[1][ct], 0, 0, 0);
            acc[1][ct] = __builtin_amdgcn_mfma_f32_16x16x32_f16(a1h, bh, acc[1][ct], 0, 0, 0);
        }
    }

    const int orow = r0 + lk * 4;
#pragma unroll
    for (int rt = 0; rt < 2; ++rt) {
#pragma unroll
        for (int r = 0; r < 4; ++r) {
            int row = orow + rt * 16 + r;
            if (row < nrows) {
                float dd = dis[row];
#pragma unroll
                for (int ct = 0; ct < CT; ++ct) {
                    Y[(size_t)row * NOUT + ct * 16 + lrow] =
                        (_Float16)(dd * acc[rt][ct][r]);
                }
            }
        }
    }
}

template <int NOUT>
__global__ __launch_bounds__(256) void gemm_mfma(const _Float16* __restrict__ Xhi,
                                                 const _Float16* __restrict__ Xlo,
                                                 const _Float16* __restrict__ WThi,
                                                 const _Float16* __restrict__ WTlo,
                                                 const float* __restrict__ dis,
                                                 _Float16* __restrict__ Y, int nrows) {
    gemm_core<NOUT, false>((const half8*)Xhi, (const half8*)Xlo, WThi, WTlo, dis, Y,
                           nrows, nullptr);
}

// layer-1 variant: reads fp32 X directly, splits in-register (no xsplit pass)
__global__ __launch_bounds__(256) void gemm_mfma_l1(const float* __restrict__ X,
                                                    const _Float16* __restrict__ WThi,
                                                    const _Float16* __restrict__ WTlo,
                                                    const float* __restrict__ dis,
                                                    _Float16* __restrict__ Y, int nrows) {
    gemm_core<128, true>(nullptr, nullptr, WThi, WTlo, dis, Y, nrows,
                         (const float4*)X);
}

// ---------------------------------------------------------------------------
// Aggregation: ONE WAVE per node, 4 nodes per block. TWO rows per gather
// instruction (lanes 0..31 = even edge, lanes 32..63 = odd edge; 8B/lane
// F=128, 4B/lane F=64). shfl_xor(32) combine. NO per-thread arrays.
// ---------------------------------------------------------------------------
template <int F, bool RELU, bool SPLIT>
__global__ __launch_bounds__(256) void agg_kernel(const __half* __restrict__ h,
                                                  const float* __restrict__ dis,
                                                  const int* __restrict__ offs,
                                                  const int* __restrict__ csr_s,
                                                  const float* __restrict__ bias,
                                                  float* __restrict__ outf,
                                                  __half* __restrict__ ohi,
                                                  __half* __restrict__ olo, int n) {
    const int d = blockIdx.x * 4 + (threadIdx.x >> 6);
    if (d >= n) return;
    const int lane = threadIdx.x & 63;
    const int li = lane & 31;
    const bool upper = lane >= 32;
    const int beg = offs[d];
    const int end = offs[d + 1];

    if constexpr (F == 128) {
        const uint2* hv = (const uint2*)h;   // 32 uint2 per row
        float a0 = 0.f, a1 = 0.f, a2 = 0.f, a3 = 0.f;
        int i = beg;
        for (; i + 16 <= end; i += 16) {     // 8 pairs in flight
            int s0 = csr_s[i + 0],  s1 = csr_s[i + 1];
            int s2 = csr_s[i + 2],  s3 = csr_s[i + 3];
            int s4 = csr_s[i + 4],  s5 = csr_s[i + 5];
            int s6 = csr_s[i + 6],  s7 = csr_s[i + 7];
            int s8 = csr_s[i + 8],  s9 = csr_s[i + 9];
            int sa = csr_s[i + 10], sb = csr_s[i + 11];
            int sc = csr_s[i + 12], sd = csr_s[i + 13];
            int se = csr_s[i + 14], sf = csr_s[i + 15];
            uint2 v0 = hv[(size_t)(upper ? s1 : s0) * 32 + li];
            uint2 v1 = hv[(size_t)(upper ? s3 : s2) * 32 + li];
            uint2 v2 = hv[(size_t)(upper ? s5 : s4) * 32 + li];
            uint2 v3 = hv[(size_t)(upper ? s7 : s6) * 32 + li];
            uint2 v4 = hv[(size_t)(upper ? s9 : s8) * 32 + li];
            uint2 v5 = hv[(size_t)(upper ? sb : sa) * 32 + li];
            uint2 v6 = hv[(size_t)(upper ? sd : sc) * 32 + li];
            uint2 v7 = hv[(size_t)(upper ? sf : se) * 32 + li];
            float2 f;
            f = __half22float2(*reinterpret_cast<__half2*>(&v0.x)); a0 += f.x; a1 += f.y;
            f = __half22float2(*reinterpret_cast<__half2*>(&v0.y)); a2 += f.x; a3 += f.y;
            f = __half22float2(*reinterpret_cast<__half2*>(&v1.x)); a0 += f.x; a1 += f.y;
            f = __half22float2(*reinterpret_cast<__half2*>(&v1.y)); a2 += f.x; a3 += f.y;
            f = __half22float2(*reinterpret_cast<__half2*>(&v2.x)); a0 += f.x; a1 += f.y;
            f = __half22float2(*reinterpret_cast<__half2*>(&v2.y)); a2 += f.x; a3 += f.y;
            f = __half22float2(*reinterpret_cast<__half2*>(&v3.x)); a0 += f.x; a1 += f.y;
            f = __half22float2(*reinterpret_cast<__half2*>(&v3.y)); a2 += f.x; a3 += f.y;
            f = __half22float2(*reinterpret_cast<__half2*>(&v4.x)); a0 += f.x; a1 += f.y;
            f = __half22float2(*reinterpret_cast<__half2*>(&v4.y)); a2 += f.x; a3 += f.y;
            f = __half22float2(*reinterpret_cast<__half2*>(&v5.x)); a0 += f.x; a1 += f.y;
            f = __half22float2(*reinterpret_cast<__half2*>(&v5.y)); a2 += f.x; a3 += f.y;
            f = __half22float2(*reinterpret_cast<__half2*>(&v6.x)); a0 += f.x; a1 += f.y;
            f = __half22float2(*reinterpret_cast<__half2*>(&v6.y)); a2 += f.x; a3 += f.y;
            f = __half22float2(*reinterpret_cast<__half2*>(&v7.x)); a0 += f.x; a1 += f.y;
            f = __half22float2(*reinterpret_cast<__half2*>(&v7.y)); a2 += f.x; a3 += f.y;
        }
        for (; i + 2 <= end; i += 2) {       // single pairs
            int s0 = csr_s[i], s1 = csr_s[i + 1];
            uint2 v = hv[(size_t)(upper ? s1 : s0) * 32 + li];
            float2 f0 = __half22float2(*reinterpret_cast<__half2*>(&v.x));
            float2 f1 = __half22float2(*reinterpret_cast<__half2*>(&v.y));
            a0 += f0.x; a1 += f0.y; a2 += f1.x; a3 += f1.y;
        }
        {   // odd tail edge (lower half) + self row (upper half)
            int row = -1;
            if (!upper) {
                if (i < end) row = csr_s[i];
            } else {
                row = d;
            }
            if (row >= 0) {
                uint2 v = hv[(size_t)row * 32 + li];
                float2 f0 = __half22float2(*reinterpret_cast<__half2*>(&v.x));
                float2 f1 = __half22float2(*reinterpret_cast<__half2*>(&v.y));
                a0 += f0.x; a1 += f0.y; a2 += f1.x; a3 += f1.y;
            }
        }
        a0 += __shfl_xor(a0, 32);
        a1 += __shfl_xor(a1, 32);
        a2 += __shfl_xor(a2, 32);
        a3 += __shfl_xor(a3, 32);
        if (!upper) {
            float dd = dis[d];
            float4 b4 = ((const float4*)bias)[li];
            float r0 = fmaf(dd, a0, b4.x);
            float r1 = fmaf(dd, a1, b4.y);
            float r2 = fmaf(dd, a2, b4.z);
            float r3 = fmaf(dd, a3, b4.w);
            if (RELU) {
                r0 = fmaxf(r0, 0.f); r1 = fmaxf(r1, 0.f);
                r2 = fmaxf(r2, 0.f); r3 = fmaxf(r3, 0.f);
            }
            if constexpr (SPLIT) {
                __half h0 = __float2half(r0), h1 = __float2half(r1);
                __half h2 = __float2half(r2), h3 = __float2half(r3);
                __half2 hh01 = __halves2half2(h0, h1), hh23 = __halves2half2(h2, h3);
                uint2 uh;
                uh.x = *reinterpret_cast<unsigned*>(&hh01);
                uh.y = *reinterpret_cast<unsigned*>(&hh23);
                ((uint2*)ohi)[(size_t)d * 32 + li] = uh;
                __half l0 = __float2half(r0 - __half2float(h0));
                __half l1 = __float2half(r1 - __half2float(h1));
                __half l2 = __float2half(r2 - __half2float(h2));
                __half l3 = __float2half(r3 - __half2float(h3));
                __half2 ll01 = __halves2half2(l0, l1), ll23 = __halves2half2(l2, l3);
                uint2 ul;
                ul.x = *reinterpret_cast<unsigned*>(&ll01);
                ul.y = *reinterpret_cast<unsigned*>(&ll23);
                ((uint2*)olo)[(size_t)d * 32 + li] = ul;
            } else {
                ((float4*)outf)[(size_t)d * 32 + li] = make_float4(r0, r1, r2, r3);
            }
        }
    } else {   // F == 64
        const unsigned* hv = (const unsigned*)h;   // 32 uints per row
        float a0 = 0.f, a1 = 0.f;
        int i = beg;
        for (; i + 16 <= end; i += 16) {
            int s0 = csr_s[i + 0],  s1 = csr_s[i + 1];
            int s2 = csr_s[i + 2],  s3 = csr_s[i + 3];
            int s4 = csr_s[i + 4],  s5 = csr_s[i + 5];
            int s6 = csr_s[i + 6],  s7 = csr_s[i + 7];
            int s8 = csr_s[i + 8],  s9 = csr_s[i + 9];
            int sa = csr_s[i + 10], sb = csr_s[i + 11];
            int sc = csr_s[i + 12], sd = csr_s[i + 13];
            int se = csr_s[i + 14], sf = csr_s[i + 15];
            unsigned v0 = hv[(size_t)(upper ? s1 : s0) * 32 + li];
            unsigned v1 = hv[(size_t)(upper ? s3 : s2) * 32 + li];
            unsigned v2 = hv[(size_t)(upper ? s5 : s4) * 32 + li];
            unsigned v3 = hv[(size_t)(upper ? s7 : s6) * 32 + li];
            unsigned v4 = hv[(size_t)(upper ? s9 : s8) * 32 + li];
            unsigned v5 = hv[(size_t)(upper ? sb : sa) * 32 + li];
            unsigned v6 = hv[(size_t)(upper ? sd : sc) * 32 + li];
            unsigned v7 = hv[(size_t)(upper ? sf : se) * 32 + li];
            float2 f;
            f = __half22float2(*reinterpret_cast<__half2*>(&v0)); a0 += f.x; a1 += f.y;
            f = __half22float2(*reinterpret_cast<__half2*>(&v1)); a0 += f.x; a1 += f.y;
            f = __half22float2(*reinterpret_cast<__half2*>(&v2)); a0 += f.x; a1 += f.y;
            f = __half22float2(*reinterpret_cast<__half2*>(&v3)); a0 += f.x; a1 += f.y;
            f = __half22float2(*reinterpret_cast<__half2*>(&v4)); a0 += f.x; a1 += f.y;
            f = __half22float2(*reinterpret_cast<__half2*>(&v5)); a0 += f.x; a1 += f.y;
            f = __half22float2(*reinterpret_cast<__half2*>(&v6)); a0 += f.x; a1 += f.y;
            f = __half22float2(*reinterpret_cast<__half2*>(&v7)); a0 += f.x; a1 += f.y;
        }
        for (; i + 2 <= end; i += 2) {
            int s0 = csr_s[i], s1 = csr_s[i + 1];
            unsigned v = hv[(size_t)(upper ? s1 : s0) * 32 + li];
            float2 f = __half22float2(*reinterpret_cast<__half2*>(&v));
            a0 += f.x; a1 += f.y;
        }
        {
            int row = -1;
            if (!upper) {
                if (i < end) row = csr_s[i];
            } else {
                row = d;
            }
            if (row >= 0) {
                unsigned v = hv[(size_t)row * 32 + li];
                float2 f = __half22float2(*reinterpret_cast<__half2*>(&v));
                a0 += f.x; a1 += f.y;
            }
        }
        a0 += __shfl_xor(a0, 32);
        a1 += __shfl_xor(a1, 32);
        if (!upper) {
            float dd = dis[d];
            float2 b2 = ((const float2*)bias)[li];
            float r0 = fmaf(dd, a0, b2.x);
            float r1 = fmaf(dd, a1, b2.y);
            if (RELU) {
                r0 = fmaxf(r0, 0.f);
                r1 = fmaxf(r1, 0.f);
            }
            ((float2*)outf)[(size_t)d * 32 + li] = make_float2(r0, r1);
        }
    }
}

// ---------------------------------------------------------------------------

extern "C" void kernel_launch(void* const* d_in, const int* in_sizes, int n_in,
                              void* d_out, int out_size, void* d_ws, size_t ws_size,
                              hipStream_t stream) {
    const float* x  = (const float*)d_in[0];
    const int*   ei = (const int*)d_in[1];
    const float* W1 = (const float*)d_in[2];
    const float* b1 = (const float*)d_in[3];
    const float* W2 = (const float*)d_in[4];
    const float* b2 = (const float*)d_in[5];
    const float* W3 = (const float*)d_in[6];
    const float* b3 = (const float*)d_in[7];

    const int N = in_sizes[0] / 128;
    const int E = in_sizes[1] / 2;
    const int* src = ei;
    const int* dst = ei + E;
    float* out = (float*)d_out;

    char* w = (char*)d_ws;
    auto take = [&](size_t bytes) -> void* {
        void* p = (void*)w;
        w += (bytes + 255) & ~(size_t)255;
        return p;
    };
    int*      counts = (int*)take((size_t)N * 4);
    int*      offs   = (int*)take((size_t)(N + 1) * 4);
    float*    dis    = (float*)take((size_t)N * 4);
    int*      bsum   = (int*)take((size_t)1024 * 4);
    int*      csr_s  = (int*)take((size_t)E * 4);
    _Float16* G16    = (_Float16*)take((size_t)N * 128 * 2);  // prescaled fp16 rows
    _Float16* Xhi    = (_Float16*)take((size_t)N * 128 * 2);  // GEMM input hi
    _Float16* Xlo    = (_Float16*)take((size_t)N * 128 * 2);  // GEMM input lo
    _Float16* Whi    = (_Float16*)take((size_t)40960 * 2);
    _Float16* Wlo    = (_Float16*)take((size_t)40960 * 2);
    // rank is only live between count_kernel and fill_kernel; G16 is only
    // written from the first GEMM onward (same stream => sequential). Alias.
    int*      rank   = (int*)G16;

    const int NBLK = (N + 256) / 256;

    // --- graph preprocessing ---
    hipMemsetAsync(counts, 0, (size_t)N * 4, stream);
    count_kernel<<<2048, 256, 0, stream>>>(dst, counts, rank, E);
    block_sum_kernel<<<NBLK, 256, 0, stream>>>(counts, bsum, N);
    small_scan_kernel<<<1, 256, 0, stream>>>(bsum, NBLK);
    scan_block_kernel<<<NBLK, 256, 0, stream>>>(counts, bsum, offs, dis, N, E);
    fill_kernel<<<2048, 256, 0, stream>>>(src, dst, offs, rank, csr_s, E);

    // --- weight split (160 KB, trivial) ---
    wsplit_kernel<<<160, 256, 0, stream>>>(W1, W2, W3, Whi, Wlo);

    const int gblocks = (N + 127) / 128;   // 128 rows per block (4 waves x 32)
    const int ablocks = (N + 3) / 4;

    // layer 1 (fp32 X split in-register)
    gemm_mfma_l1<<<gblocks, 256, 0, stream>>>(x, Whi, Wlo, dis, G16, N);
    agg_kernel<128, true, true><<<ablocks, 256, 0, stream>>>(
        (const __half*)G16, dis, offs, csr_s, b1, nullptr, (__half*)Xhi, (__half*)Xlo, N);
    // layer 2
    gemm_mfma<128><<<gblocks, 256, 0, stream>>>(Xhi, Xlo, Whi + 16384, Wlo + 16384,
                                                dis, G16, N);
    agg_kernel<128, true, true><<<ablocks, 256, 0, stream>>>(
        (const __half*)G16, dis, offs, csr_s, b2, nullptr, (__half*)Xhi, (__half*)Xlo, N);
    // layer 3
    gemm_mfma<64><<<gblocks, 256, 0, stream>>>(Xhi, Xlo, Whi + 32768, Wlo + 32768,
                                               dis, G16, N);
    agg_kernel<64, false, false><<<ablocks, 256, 0, stream>>>(
        (const __half*)G16, dis, offs, csr_s, b3, out, nullptr, nullptr, N);
}

// Round 12
// 218.381 us; speedup vs baseline: 1.5427x; 1.1356x over previous
//
#include <hip/hip_runtime.h>
#include <hip/hip_fp16.h>
#include <math.h>

// ---------------------------------------------------------------------------
// GCN 3-layer. Per layer: P = X@W via split-fp16 MFMA (fp32-grade accuracy),
// epilogue stores P' = dis_r*P_r as fp16. agg: out[d] = dis_d*(sum P'[src] +
// P'[d]) + b. agg: 16-lane group reads ONE row as uint4/lane => 4 rows per
// VMEM instruction (F=128); 8-lane groups => 8 rows/instr (F=64).
// Tail folds the self-row into the last 4-row gather (groups>m re-read row d
// with weight 0 -- same cache line, no wasted HBM). Named scalars only
// (R9 lesson: LLVM PromoteAlloca demotes per-thread arrays to LDS).
// ---------------------------------------------------------------------------

typedef _Float16 half8 __attribute__((ext_vector_type(8)));
typedef float f32x4 __attribute__((ext_vector_type(4)));

// counts in-degree AND records each edge's rank within its dst bucket
__global__ void count_kernel(const int* __restrict__ dst, int* __restrict__ counts,
                             int* __restrict__ rank, int E) {
    int i = blockIdx.x * blockDim.x + threadIdx.x;
    int st = gridDim.x * blockDim.x;
    for (; i < E; i += st) rank[i] = atomicAdd(&counts[dst[i]], 1);
}

// --------------------------- multi-block scan ------------------------------
__global__ __launch_bounds__(256) void block_sum_kernel(const int* __restrict__ counts,
                                                        int* __restrict__ bsum, int n) {
    const int b = blockIdx.x;
    const int t = threadIdx.x;
    const int idx = b * 256 + t;
    int v = (idx < n) ? counts[idx] : 0;
#pragma unroll
    for (int o = 32; o > 0; o >>= 1) v += __shfl_down(v, o, 64);
    __shared__ int ws[4];
    if ((t & 63) == 0) ws[t >> 6] = v;
    __syncthreads();
    if (t == 0) bsum[b] = ws[0] + ws[1] + ws[2] + ws[3];
}

__global__ __launch_bounds__(256) void small_scan_kernel(int* __restrict__ bsum, int nb) {
    __shared__ int sm[256];
    const int t = threadIdx.x;
    int v = (t < nb) ? bsum[t] : 0;
    sm[t] = v;
    __syncthreads();
    for (int o = 1; o < 256; o <<= 1) {
        int x = (t >= o) ? sm[t - o] : 0;
        __syncthreads();
        sm[t] += x;
        __syncthreads();
    }
    if (t < nb) bsum[t] = sm[t] - v;   // exclusive
}

// scan within block + write dis (fused)
__global__ __launch_bounds__(256) void scan_block_kernel(const int* __restrict__ counts,
                                                         const int* __restrict__ bsum,
                                                         int* __restrict__ offs,
                                                         float* __restrict__ dis,
                                                         int n, int E) {
    const int b = blockIdx.x;
    const int t = threadIdx.x;
    const int idx = b * 256 + t;
    int v = (idx < n) ? counts[idx] : 0;
    if (idx < n) dis[idx] = rsqrtf((float)(v + 1));   // +1 self-loop
    __shared__ int sm[256];
    sm[t] = v;
    __syncthreads();
    for (int o = 1; o < 256; o <<= 1) {
        int x = (t >= o) ? sm[t - o] : 0;
        __syncthreads();
        sm[t] += x;
        __syncthreads();
    }
    if (idx < n) offs[idx] = bsum[b] + sm[t] - v;   // exclusive prefix
    if (idx == n) offs[n] = E;
}

__global__ void fill_kernel(const int* __restrict__ src, const int* __restrict__ dst,
                            const int* __restrict__ offs, const int* __restrict__ rank,
                            int* __restrict__ csr_s, int E) {
    int i = blockIdx.x * blockDim.x + threadIdx.x;
    int st = gridDim.x * blockDim.x;
    for (; i < E; i += st) {
        int p = offs[dst[i]] + rank[i];
        csr_s[p] = src[i];
    }
}

// W1,W2 (128x128), W3 (128x64) -> transposed WT[c][k] hi/lo fp16.
__global__ __launch_bounds__(256) void wsplit_kernel(const float* __restrict__ W1,
                                                     const float* __restrict__ W2,
                                                     const float* __restrict__ W3,
                                                     _Float16* __restrict__ hi,
                                                     _Float16* __restrict__ lo) {
    int idx = blockIdx.x * 256 + threadIdx.x;
    if (idx >= 40960) return;
    float v;
    if (idx < 16384) {
        int c = idx >> 7, k = idx & 127;
        v = W1[k * 128 + c];
    } else if (idx < 32768) {
        int j = idx - 16384;
        int c = j >> 7, k = j & 127;
        v = W2[k * 128 + c];
    } else {
        int j = idx - 32768;
        int c = j >> 7, k = j & 127;
        v = W3[k * 64 + c];
    }
    _Float16 h = (_Float16)v;
    hi[idx] = h;
    lo[idx] = (_Float16)(v - (float)h);
}

// ---------------------------------------------------------------------------
// MFMA GEMM cores (unchanged from R10). 16x16x32 fragment maps:
// A: row=l&15, k=8*(l>>4)+j. B: col=l&15, k=8*(l>>4)+j. C/D: col=l&15,
// row=(l>>4)*4+reg. 4 waves/block, 32 rows/wave. WT[c][k].
// ---------------------------------------------------------------------------
template <int NOUT, bool FROM_F32>
__device__ __forceinline__ void gemm_core(const half8* __restrict__ XhiV,
                                          const half8* __restrict__ XloV,
                                          const _Float16* __restrict__ WThi,
                                          const _Float16* __restrict__ WTlo,
                                          const float* __restrict__ dis,
                                          _Float16* __restrict__ Y, int nrows,
                                          const float4* X4) {
    constexpr int CT = NOUT / 16;
    const int wave = threadIdx.x >> 6;
    const int lane = threadIdx.x & 63;
    const int lrow = lane & 15;
    const int lk = lane >> 4;
    const int r0 = (blockIdx.x * 4 + wave) * 32;

    const f32x4 Z = {0.f, 0.f, 0.f, 0.f};
    f32x4 acc[2][CT];
#pragma unroll
    for (int a = 0; a < 2; ++a)
#pragma unroll
        for (int b = 0; b < CT; ++b) acc[a][b] = Z;

    const half8* WhiV = (const half8*)WThi;
    const half8* WloV = (const half8*)WTlo;

    int ar0 = r0 + lrow;
    int ar1 = r0 + 16 + lrow;
    if (ar0 > nrows - 1) ar0 = nrows - 1;
    if (ar1 > nrows - 1) ar1 = nrows - 1;

#pragma unroll
    for (int ks = 0; ks < 4; ++ks) {
        const int kidx = ks * 4 + lk;
        half8 a0h, a0l, a1h, a1l;
        if constexpr (FROM_F32) {
            float4 u0 = X4[(size_t)ar0 * 32 + 2 * kidx];
            float4 u1 = X4[(size_t)ar0 * 32 + 2 * kidx + 1];
            float4 w0 = X4[(size_t)ar1 * 32 + 2 * kidx];
            float4 w1 = X4[(size_t)ar1 * 32 + 2 * kidx + 1];
            float v0[8] = {u0.x, u0.y, u0.z, u0.w, u1.x, u1.y, u1.z, u1.w};
            float v1[8] = {w0.x, w0.y, w0.z, w0.w, w1.x, w1.y, w1.z, w1.w};
#pragma unroll
            for (int j = 0; j < 8; ++j) {
                _Float16 hh = (_Float16)v0[j];
                a0h[j] = hh;
                a0l[j] = (_Float16)(v0[j] - (float)hh);
                _Float16 gg = (_Float16)v1[j];
                a1h[j] = gg;
                a1l[j] = (_Float16)(v1[j] - (float)gg);
            }
        } else {
            a0h = XhiV[(size_t)ar0 * 16 + kidx];
            a0l = XloV[(size_t)ar0 * 16 + kidx];
            a1h = XhiV[(size_t)ar1 * 16 + kidx];
            a1l = XloV[(size_t)ar1 * 16 + kidx];
        }
#pragma unroll
        for (int ct = 0; ct < CT; ++ct) {
            const size_t bidx = (size_t)(ct * 16 + lrow) * 16 + kidx;
            half8 bh = WhiV[bidx];
            half8 bl = WloV[bidx];
            acc[0][ct] = __builtin_amdgcn_mfma_f32_16x16x32_f16(a0l, bh, acc[0][ct], 0, 0, 0);
            acc[0][ct] = __builtin_amdgcn_mfma_f32_16x16x32_f16(a0h, bl, acc[0][ct], 0, 0, 0);
            acc[0][ct] = __builtin_amdgcn_mfma_f32_16x16x32_f16(a0h, bh, acc[0][ct], 0, 0, 0);
            acc[1][ct] = __builtin_amdgcn_mfma_f32_16x16x32_f16(a1l, bh, acc[1][ct], 0, 0, 0);
            acc[1][ct] = __builtin_amdgcn_mfma_f32_16x16x32_f16(a1h, bl, acc[1][ct], 0, 0, 0);
            acc[1][ct] = __builtin_amdgcn_mfma_f32_16x16x32_f16(a1h, bh, acc[1][ct], 0, 0, 0);
        }
    }

    const int orow = r0 + lk * 4;
#pragma unroll
    for (int rt = 0; rt < 2; ++rt) {
#pragma unroll
        for (int r = 0; r < 4; ++r) {
            int row = orow + rt * 16 + r;
            if (row < nrows) {
                float dd = dis[row];
#pragma unroll
                for (int ct = 0; ct < CT; ++ct) {
                    Y[(size_t)row * NOUT + ct * 16 + lrow] =
                        (_Float16)(dd * acc[rt][ct][r]);
                }
            }
        }
    }
}

template <int NOUT>
__global__ __launch_bounds__(256) void gemm_mfma(const _Float16* __restrict__ Xhi,
                                                 const _Float16* __restrict__ Xlo,
                                                 const _Float16* __restrict__ WThi,
                                                 const _Float16* __restrict__ WTlo,
                                                 const float* __restrict__ dis,
                                                 _Float16* __restrict__ Y, int nrows) {
    gemm_core<NOUT, false>((const half8*)Xhi, (const half8*)Xlo, WThi, WTlo, dis, Y,
                           nrows, nullptr);
}

// layer-1 variant: reads fp32 X directly, splits in-register (no xsplit pass)
__global__ __launch_bounds__(256) void gemm_mfma_l1(const float* __restrict__ X,
                                                    const _Float16* __restrict__ WThi,
                                                    const _Float16* __restrict__ WTlo,
                                                    const float* __restrict__ dis,
                                                    _Float16* __restrict__ Y, int nrows) {
    gemm_core<128, true>(nullptr, nullptr, WThi, WTlo, dis, Y, nrows,
                         (const float4*)X);
}

// ---------------------------------------------------------------------------
// agg helpers: accumulate 8 fp16 (one uint4) into a0..a7.
// Macro params prefixed to avoid colliding with vector member tokens (.w!).
// ---------------------------------------------------------------------------
#define ACC8(_v)                                                                    \
    do {                                                                            \
        float2 _f;                                                                  \
        _f = __half22float2(*reinterpret_cast<const __half2*>(&(_v).x));            \
        a0 += _f.x; a1 += _f.y;                                                     \
        _f = __half22float2(*reinterpret_cast<const __half2*>(&(_v).y));            \
        a2 += _f.x; a3 += _f.y;                                                     \
        _f = __half22float2(*reinterpret_cast<const __half2*>(&(_v).z));            \
        a4 += _f.x; a5 += _f.y;                                                     \
        _f = __half22float2(*reinterpret_cast<const __half2*>(&(_v).w));            \
        a6 += _f.x; a7 += _f.y;                                                     \
    } while (0)

#define ACC8W(_v, _scale)                                                           \
    do {                                                                            \
        float2 _f;                                                                  \
        _f = __half22float2(*reinterpret_cast<const __half2*>(&(_v).x));            \
        a0 = fmaf((_scale), _f.x, a0); a1 = fmaf((_scale), _f.y, a1);               \
        _f = __half22float2(*reinterpret_cast<const __half2*>(&(_v).y));            \
        a2 = fmaf((_scale), _f.x, a2); a3 = fmaf((_scale), _f.y, a3);               \
        _f = __half22float2(*reinterpret_cast<const __half2*>(&(_v).z));            \
        a4 = fmaf((_scale), _f.x, a4); a5 = fmaf((_scale), _f.y, a5);               \
        _f = __half22float2(*reinterpret_cast<const __half2*>(&(_v).w));            \
        a6 = fmaf((_scale), _f.x, a6); a7 = fmaf((_scale), _f.y, a7);               \
    } while (0)

// ---------------------------------------------------------------------------
// agg F=128: one wave/node; 16-lane group reads one 256B row (uint4/lane).
// 4 rows per gather instruction. Tail gather folds self-row (w=0 dups of d).
// ---------------------------------------------------------------------------
template <bool RELU, bool SPLIT>
__global__ __launch_bounds__(256) void agg128_kernel(const __half* __restrict__ h,
                                                     const float* __restrict__ dis,
                                                     const int* __restrict__ offs,
                                                     const int* __restrict__ csr_s,
                                                     const float* __restrict__ bias,
                                                     float* __restrict__ outf,
                                                     __half* __restrict__ ohi,
                                                     __half* __restrict__ olo, int n) {
    const int d = blockIdx.x * 4 + (threadIdx.x >> 6);
    if (d >= n) return;
    const int lane = threadIdx.x & 63;
    const int g = lane >> 4;     // row group 0..3
    const int p = lane & 15;     // uint4 position within the row
    const int beg = offs[d];
    const int end = offs[d + 1];
    const uint4* hv = (const uint4*)h;   // 16 uint4 per row

    float a0 = 0.f, a1 = 0.f, a2 = 0.f, a3 = 0.f;
    float a4 = 0.f, a5 = 0.f, a6 = 0.f, a7 = 0.f;

    int i = beg;
    for (; i + 16 <= end; i += 16) {     // 4 gathers (16 rows) in flight
        int r0 = csr_s[i + g];
        int r1 = csr_s[i + 4 + g];
        int r2 = csr_s[i + 8 + g];
        int r3 = csr_s[i + 12 + g];
        uint4 v0 = hv[(size_t)r0 * 16 + p];
        uint4 v1 = hv[(size_t)r1 * 16 + p];
        uint4 v2 = hv[(size_t)r2 * 16 + p];
        uint4 v3 = hv[(size_t)r3 * 16 + p];
        ACC8(v0); ACC8(v1); ACC8(v2); ACC8(v3);
    }
    if (i + 8 <= end) {
        int r0 = csr_s[i + g];
        int r1 = csr_s[i + 4 + g];
        uint4 v0 = hv[(size_t)r0 * 16 + p];
        uint4 v1 = hv[(size_t)r1 * 16 + p];
        ACC8(v0); ACC8(v1);
        i += 8;
    }
    if (i + 4 <= end) {
        int r0 = csr_s[i + g];
        uint4 v0 = hv[(size_t)r0 * 16 + p];
        ACC8(v0);
        i += 4;
    }
    {   // tail: m in [0,3] residual edges; group m = self row; groups>m zero
        int m = end - i;
        int row = (g < m) ? csr_s[i + g] : d;
        float wt = (g <= m) ? 1.f : 0.f;
        uint4 v = hv[(size_t)row * 16 + p];
        ACC8W(v, wt);
    }

    a0 += __shfl_xor(a0, 16); a0 += __shfl_xor(a0, 32);
    a1 += __shfl_xor(a1, 16); a1 += __shfl_xor(a1, 32);
    a2 += __shfl_xor(a2, 16); a2 += __shfl_xor(a2, 32);
    a3 += __shfl_xor(a3, 16); a3 += __shfl_xor(a3, 32);
    a4 += __shfl_xor(a4, 16); a4 += __shfl_xor(a4, 32);
    a5 += __shfl_xor(a5, 16); a5 += __shfl_xor(a5, 32);
    a6 += __shfl_xor(a6, 16); a6 += __shfl_xor(a6, 32);
    a7 += __shfl_xor(a7, 16); a7 += __shfl_xor(a7, 32);

    if (lane < 16) {   // lanes 0..15 own feats 8p..8p+7
        float dd = dis[d];
        float4 b0 = ((const float4*)bias)[2 * p];
        float4 b1 = ((const float4*)bias)[2 * p + 1];
        float r0 = fmaf(dd, a0, b0.x);
        float r1 = fmaf(dd, a1, b0.y);
        float r2 = fmaf(dd, a2, b0.z);
        float r3 = fmaf(dd, a3, b0.w);
        float r4 = fmaf(dd, a4, b1.x);
        float r5 = fmaf(dd, a5, b1.y);
        float r6 = fmaf(dd, a6, b1.z);
        float r7 = fmaf(dd, a7, b1.w);
        if (RELU) {
            r0 = fmaxf(r0, 0.f); r1 = fmaxf(r1, 0.f);
            r2 = fmaxf(r2, 0.f); r3 = fmaxf(r3, 0.f);
            r4 = fmaxf(r4, 0.f); r5 = fmaxf(r5, 0.f);
            r6 = fmaxf(r6, 0.f); r7 = fmaxf(r7, 0.f);
        }
        if constexpr (SPLIT) {
            __half h0 = __float2half(r0), h1 = __float2half(r1);
            __half h2 = __float2half(r2), h3 = __float2half(r3);
            __half h4 = __float2half(r4), h5 = __float2half(r5);
            __half h6 = __float2half(r6), h7 = __float2half(r7);
            __half2 q0 = __halves2half2(h0, h1), q1 = __halves2half2(h2, h3);
            __half2 q2 = __halves2half2(h4, h5), q3 = __halves2half2(h6, h7);
            uint4 uh;
            uh.x = *reinterpret_cast<unsigned*>(&q0);
            uh.y = *reinterpret_cast<unsigned*>(&q1);
            uh.z = *reinterpret_cast<unsigned*>(&q2);
            uh.w = *reinterpret_cast<unsigned*>(&q3);
            ((uint4*)ohi)[(size_t)d * 16 + p] = uh;
            __half2 l0 = __halves2half2(__float2half(r0 - __half2float(h0)),
                                        __float2half(r1 - __half2float(h1)));
            __half2 l1 = __halves2half2(__float2half(r2 - __half2float(h2)),
                                        __float2half(r3 - __half2float(h3)));
            __half2 l2 = __halves2half2(__float2half(r4 - __half2float(h4)),
                                        __float2half(r5 - __half2float(h5)));
            __half2 l3 = __halves2half2(__float2half(r6 - __half2float(h6)),
                                        __float2half(r7 - __half2float(h7)));
            uint4 ul;
            ul.x = *reinterpret_cast<unsigned*>(&l0);
            ul.y = *reinterpret_cast<unsigned*>(&l1);
            ul.z = *reinterpret_cast<unsigned*>(&l2);
            ul.w = *reinterpret_cast<unsigned*>(&l3);
            ((uint4*)olo)[(size_t)d * 16 + p] = ul;
        } else {
            ((float4*)outf)[(size_t)d * 32 + 2 * p] = make_float4(r0, r1, r2, r3);
            ((float4*)outf)[(size_t)d * 32 + 2 * p + 1] = make_float4(r4, r5, r6, r7);
        }
    }
}

// ---------------------------------------------------------------------------
// agg F=64 (final layer, fp32 out): 8-lane group reads one 128B row
// (uint4/lane). 8 rows per gather instruction. Same tail trick (m in [0,7]).
// ---------------------------------------------------------------------------
__global__ __launch_bounds__(256) void agg64_kernel(const __half* __restrict__ h,
                                                    const float* __restrict__ dis,
                                                    const int* __restrict__ offs,
                                                    const int* __restrict__ csr_s,
                                                    const float* __restrict__ bias,
                                                    float* __restrict__ outf, int n) {
    const int d = blockIdx.x * 4 + (threadIdx.x >> 6);
    if (d >= n) return;
    const int lane = threadIdx.x & 63;
    const int g = lane >> 3;     // row group 0..7
    const int p = lane & 7;      // uint4 position within the row
    const int beg = offs[d];
    const int end = offs[d + 1];
    const uint4* hv = (const uint4*)h;   // 8 uint4 per row

    float a0 = 0.f, a1 = 0.f, a2 = 0.f, a3 = 0.f;
    float a4 = 0.f, a5 = 0.f, a6 = 0.f, a7 = 0.f;

    int i = beg;
    for (; i + 16 <= end; i += 16) {     // 2 gathers (16 rows) in flight
        int r0 = csr_s[i + g];
        int r1 = csr_s[i + 8 + g];
        uint4 v0 = hv[(size_t)r0 * 8 + p];
        uint4 v1 = hv[(size_t)r1 * 8 + p];
        ACC8(v0); ACC8(v1);
    }
    if (i + 8 <= end) {
        int r0 = csr_s[i + g];
        uint4 v0 = hv[(size_t)r0 * 8 + p];
        ACC8(v0);
        i += 8;
    }
    {   // tail: m in [0,7]; group m = self row; groups>m zero
        int m = end - i;
        int row = (g < m) ? csr_s[i + g] : d;
        float wt = (g <= m) ? 1.f : 0.f;
        uint4 v = hv[(size_t)row * 8 + p];
        ACC8W(v, wt);
    }

    a0 += __shfl_xor(a0, 8); a0 += __shfl_xor(a0, 16); a0 += __shfl_xor(a0, 32);
    a1 += __shfl_xor(a1, 8); a1 += __shfl_xor(a1, 16); a1 += __shfl_xor(a1, 32);
    a2 += __shfl_xor(a2, 8); a2 += __shfl_xor(a2, 16); a2 += __shfl_xor(a2, 32);
    a3 += __shfl_xor(a3, 8); a3 += __shfl_xor(a3, 16); a3 += __shfl_xor(a3, 32);
    a4 += __shfl_xor(a4, 8); a4 += __shfl_xor(a4, 16); a4 += __shfl_xor(a4, 32);
    a5 += __shfl_xor(a5, 8); a5 += __shfl_xor(a5, 16); a5 += __shfl_xor(a5, 32);
    a6 += __shfl_xor(a6, 8); a6 += __shfl_xor(a6, 16); a6 += __shfl_xor(a6, 32);
    a7 += __shfl_xor(a7, 8); a7 += __shfl_xor(a7, 16); a7 += __shfl_xor(a7, 32);

    if (lane < 8) {   // lanes 0..7 own feats 8p..8p+7
        float dd = dis[d];
        float4 b0 = ((const float4*)bias)[2 * p];
        float4 b1 = ((const float4*)bias)[2 * p + 1];
        float r0 = fmaf(dd, a0, b0.x);
        float r1 = fmaf(dd, a1, b0.y);
        float r2 = fmaf(dd, a2, b0.z);
        float r3 = fmaf(dd, a3, b0.w);
        float r4 = fmaf(dd, a4, b1.x);
        float r5 = fmaf(dd, a5, b1.y);
        float r6 = fmaf(dd, a6, b1.z);
        float r7 = fmaf(dd, a7, b1.w);
        ((float4*)outf)[(size_t)d * 16 + 2 * p] = make_float4(r0, r1, r2, r3);
        ((float4*)outf)[(size_t)d * 16 + 2 * p + 1] = make_float4(r4, r5, r6, r7);
    }
}

// ---------------------------------------------------------------------------

extern "C" void kernel_launch(void* const* d_in, const int* in_sizes, int n_in,
                              void* d_out, int out_size, void* d_ws, size_t ws_size,
                              hipStream_t stream) {
    const float* x  = (const float*)d_in[0];
    const int*   ei = (const int*)d_in[1];
    const float* W1 = (const float*)d_in[2];
    const float* b1 = (const float*)d_in[3];
    const float* W2 = (const float*)d_in[4];
    const float* b2 = (const float*)d_in[5];
    const float* W3 = (const float*)d_in[6];
    const float* b3 = (const float*)d_in[7];

    const int N = in_sizes[0] / 128;
    const int E = in_sizes[1] / 2;
    const int* src = ei;
    const int* dst = ei + E;
    float* out = (float*)d_out;

    char* w = (char*)d_ws;
    auto take = [&](size_t bytes) -> void* {
        void* p = (void*)w;
        w += (bytes + 255) & ~(size_t)255;
        return p;
    };
    int*      counts = (int*)take((size_t)N * 4);
    int*      offs   = (int*)take((size_t)(N + 1) * 4);
    float*    dis    = (float*)take((size_t)N * 4);
    int*      bsum   = (int*)take((size_t)1024 * 4);
    int*      csr_s  = (int*)take((size_t)E * 4);
    _Float16* G16    = (_Float16*)take((size_t)N * 128 * 2);  // prescaled fp16 rows
    _Float16* Xhi    = (_Float16*)take((size_t)N * 128 * 2);  // GEMM input hi
    _Float16* Xlo    = (_Float16*)take((size_t)N * 128 * 2);  // GEMM input lo
    _Float16* Whi    = (_Float16*)take((size_t)40960 * 2);
    _Float16* Wlo    = (_Float16*)take((size_t)40960 * 2);
    // rank is only live between count_kernel and fill_kernel; G16 is only
    // written from the first GEMM onward (same stream => sequential). Alias.
    int*      rank   = (int*)G16;

    const int NBLK = (N + 256) / 256;

    // --- graph preprocessing ---
    hipMemsetAsync(counts, 0, (size_t)N * 4, stream);
    count_kernel<<<2048, 256, 0, stream>>>(dst, counts, rank, E);
    block_sum_kernel<<<NBLK, 256, 0, stream>>>(counts, bsum, N);
    small_scan_kernel<<<1, 256, 0, stream>>>(bsum, NBLK);
    scan_block_kernel<<<NBLK, 256, 0, stream>>>(counts, bsum, offs, dis, N, E);
    fill_kernel<<<2048, 256, 0, stream>>>(src, dst, offs, rank, csr_s, E);

    // --- weight split (160 KB, trivial) ---
    wsplit_kernel<<<160, 256, 0, stream>>>(W1, W2, W3, Whi, Wlo);

    const int gblocks = (N + 127) / 128;   // 128 rows per block (4 waves x 32)
    const int ablocks = (N + 3) / 4;

    // layer 1 (fp32 X split in-register)
    gemm_mfma_l1<<<gblocks, 256, 0, stream>>>(x, Whi, Wlo, dis, G16, N);
    agg128_kernel<true, true><<<ablocks, 256, 0, stream>>>(
        (const __half*)G16, dis, offs, csr_s, b1, nullptr, (__half*)Xhi, (__half*)Xlo, N);
    // layer 2
    gemm_mfma<128><<<gblocks, 256, 0, stream>>>(Xhi, Xlo, Whi + 16384, Wlo + 16384,
                                                dis, G16, N);
    agg128_kernel<true, true><<<ablocks, 256, 0, stream>>>(
        (const __half*)G16, dis, offs, csr_s, b2, nullptr, (__half*)Xhi, (__half*)Xlo, N);
    // layer 3
    gemm_mfma<64><<<gblocks, 256, 0, stream>>>(Xhi, Xlo, Whi + 32768, Wlo + 32768,
                                               dis, G16, N);
    agg64_kernel<<<ablocks, 256, 0, stream>>>((const __half*)G16, dis, offs, csr_s,
                                              b3, out, N);
}

// Round 13
// 214.915 us; speedup vs baseline: 1.5676x; 1.0161x over previous
//
#include <hip/hip_runtime.h>
#include <hip/hip_fp16.h>
#include <math.h>

// ---------------------------------------------------------------------------
// GCN 3-layer. Layer1: P = X@W1 via split-fp16 MFMA (X split in-register, 3
// MFMA terms -> fp32-grade). Layers 2-3: X is fp16 H (one rounding accepted),
// weights stay hi/lo (2 MFMA terms). Epilogue stores P' = dis_r*P_r fp16.
// agg: out[d] = dis_d*(sum P'[src] + P'[d]) + b; 16-lane group reads one 256B
// row as uint4/lane => 4 rows per VMEM instr (F=128); 8-lane groups => 8
// rows/instr (F=64). Tail folds self-row into the last gather. Named scalars
// only (R9: PromoteAlloca demotes per-thread arrays to LDS).
// ---------------------------------------------------------------------------

typedef _Float16 half8 __attribute__((ext_vector_type(8)));
typedef float f32x4 __attribute__((ext_vector_type(4)));

// counts in-degree AND records each edge's rank within its dst bucket
__global__ void count_kernel(const int* __restrict__ dst, int* __restrict__ counts,
                             int* __restrict__ rank, int E) {
    int i = blockIdx.x * blockDim.x + threadIdx.x;
    int st = gridDim.x * blockDim.x;
    for (; i < E; i += st) rank[i] = atomicAdd(&counts[dst[i]], 1);
}

// --------------------------- multi-block scan ------------------------------
__global__ __launch_bounds__(256) void block_sum_kernel(const int* __restrict__ counts,
                                                        int* __restrict__ bsum, int n) {
    const int b = blockIdx.x;
    const int t = threadIdx.x;
    const int idx = b * 256 + t;
    int v = (idx < n) ? counts[idx] : 0;
#pragma unroll
    for (int o = 32; o > 0; o >>= 1) v += __shfl_down(v, o, 64);
    __shared__ int ws[4];
    if ((t & 63) == 0) ws[t >> 6] = v;
    __syncthreads();
    if (t == 0) bsum[b] = ws[0] + ws[1] + ws[2] + ws[3];
}

__global__ __launch_bounds__(256) void small_scan_kernel(int* __restrict__ bsum, int nb) {
    __shared__ int sm[256];
    const int t = threadIdx.x;
    int v = (t < nb) ? bsum[t] : 0;
    sm[t] = v;
    __syncthreads();
    for (int o = 1; o < 256; o <<= 1) {
        int x = (t >= o) ? sm[t - o] : 0;
        __syncthreads();
        sm[t] += x;
        __syncthreads();
    }
    if (t < nb) bsum[t] = sm[t] - v;   // exclusive
}

// scan within block + write dis (fused)
__global__ __launch_bounds__(256) void scan_block_kernel(const int* __restrict__ counts,
                                                         const int* __restrict__ bsum,
                                                         int* __restrict__ offs,
                                                         float* __restrict__ dis,
                                                         int n, int E) {
    const int b = blockIdx.x;
    const int t = threadIdx.x;
    const int idx = b * 256 + t;
    int v = (idx < n) ? counts[idx] : 0;
    if (idx < n) dis[idx] = rsqrtf((float)(v + 1));   // +1 self-loop
    __shared__ int sm[256];
    sm[t] = v;
    __syncthreads();
    for (int o = 1; o < 256; o <<= 1) {
        int x = (t >= o) ? sm[t - o] : 0;
        __syncthreads();
        sm[t] += x;
        __syncthreads();
    }
    if (idx < n) offs[idx] = bsum[b] + sm[t] - v;   // exclusive prefix
    if (idx == n) offs[n] = E;
}

__global__ void fill_kernel(const int* __restrict__ src, const int* __restrict__ dst,
                            const int* __restrict__ offs, const int* __restrict__ rank,
                            int* __restrict__ csr_s, int E) {
    int i = blockIdx.x * blockDim.x + threadIdx.x;
    int st = gridDim.x * blockDim.x;
    for (; i < E; i += st) {
        int p = offs[dst[i]] + rank[i];
        csr_s[p] = src[i];
    }
}

// W1,W2 (128x128), W3 (128x64) -> transposed WT[c][k] hi/lo fp16.
__global__ __launch_bounds__(256) void wsplit_kernel(const float* __restrict__ W1,
                                                     const float* __restrict__ W2,
                                                     const float* __restrict__ W3,
                                                     _Float16* __restrict__ hi,
                                                     _Float16* __restrict__ lo) {
    int idx = blockIdx.x * 256 + threadIdx.x;
    if (idx >= 40960) return;
    float v;
    if (idx < 16384) {
        int c = idx >> 7, k = idx & 127;
        v = W1[k * 128 + c];
    } else if (idx < 32768) {
        int j = idx - 16384;
        int c = j >> 7, k = j & 127;
        v = W2[k * 128 + c];
    } else {
        int j = idx - 32768;
        int c = j >> 7, k = j & 127;
        v = W3[k * 64 + c];
    }
    _Float16 h = (_Float16)v;
    hi[idx] = h;
    lo[idx] = (_Float16)(v - (float)h);
}

// ---------------------------------------------------------------------------
// MFMA GEMM cores. 16x16x32 fragment maps: A: row=l&15, k=8*(l>>4)+j.
// B: col=l&15, k=8*(l>>4)+j. C/D: col=l&15, row=(l>>4)*4+reg.
// 4 waves/block, 32 rows/wave. WT[c][k] => contiguous 16B B-fragments.
// FROM_F32 (layer 1): split X in-register, 3 MFMA terms (fp32-grade X).
// else (layers 2-3): X is plain fp16, 2 MFMA terms (W stays fp32-grade).
// ---------------------------------------------------------------------------
template <int NOUT, bool FROM_F32>
__device__ __forceinline__ void gemm_core(const half8* __restrict__ XhV,
                                          const _Float16* __restrict__ WThi,
                                          const _Float16* __restrict__ WTlo,
                                          const float* __restrict__ dis,
                                          _Float16* __restrict__ Y, int nrows,
                                          const float4* X4) {
    constexpr int CT = NOUT / 16;
    const int wave = threadIdx.x >> 6;
    const int lane = threadIdx.x & 63;
    const int lrow = lane & 15;
    const int lk = lane >> 4;
    const int r0 = (blockIdx.x * 4 + wave) * 32;

    const f32x4 Z = {0.f, 0.f, 0.f, 0.f};
    f32x4 acc[2][CT];
#pragma unroll
    for (int a = 0; a < 2; ++a)
#pragma unroll
        for (int b = 0; b < CT; ++b) acc[a][b] = Z;

    const half8* WhiV = (const half8*)WThi;
    const half8* WloV = (const half8*)WTlo;

    int ar0 = r0 + lrow;
    int ar1 = r0 + 16 + lrow;
    if (ar0 > nrows - 1) ar0 = nrows - 1;
    if (ar1 > nrows - 1) ar1 = nrows - 1;

#pragma unroll
    for (int ks = 0; ks < 4; ++ks) {
        const int kidx = ks * 4 + lk;
        half8 a0h, a1h, a0l, a1l;
        if constexpr (FROM_F32) {
            float4 u0 = X4[(size_t)ar0 * 32 + 2 * kidx];
            float4 u1 = X4[(size_t)ar0 * 32 + 2 * kidx + 1];
            float4 w0 = X4[(size_t)ar1 * 32 + 2 * kidx];
            float4 w1 = X4[(size_t)ar1 * 32 + 2 * kidx + 1];
            float v0[8] = {u0.x, u0.y, u0.z, u0.w, u1.x, u1.y, u1.z, u1.w};
            float v1[8] = {w0.x, w0.y, w0.z, w0.w, w1.x, w1.y, w1.z, w1.w};
#pragma unroll
            for (int j = 0; j < 8; ++j) {
                _Float16 hh = (_Float16)v0[j];
                a0h[j] = hh;
                a0l[j] = (_Float16)(v0[j] - (float)hh);
                _Float16 gg = (_Float16)v1[j];
                a1h[j] = gg;
                a1l[j] = (_Float16)(v1[j] - (float)gg);
            }
        } else {
            a0h = XhV[(size_t)ar0 * 16 + kidx];
            a1h = XhV[(size_t)ar1 * 16 + kidx];
        }
#pragma unroll
        for (int ct = 0; ct < CT; ++ct) {
            const size_t bidx = (size_t)(ct * 16 + lrow) * 16 + kidx;
            half8 bh = WhiV[bidx];
            half8 bl = WloV[bidx];
            if constexpr (FROM_F32) {
                acc[0][ct] = __builtin_amdgcn_mfma_f32_16x16x32_f16(a0l, bh, acc[0][ct], 0, 0, 0);
                acc[1][ct] = __builtin_amdgcn_mfma_f32_16x16x32_f16(a1l, bh, acc[1][ct], 0, 0, 0);
            }
            acc[0][ct] = __builtin_amdgcn_mfma_f32_16x16x32_f16(a0h, bl, acc[0][ct], 0, 0, 0);
            acc[0][ct] = __builtin_amdgcn_mfma_f32_16x16x32_f16(a0h, bh, acc[0][ct], 0, 0, 0);
            acc[1][ct] = __builtin_amdgcn_mfma_f32_16x16x32_f16(a1h, bl, acc[1][ct], 0, 0, 0);
            acc[1][ct] = __builtin_amdgcn_mfma_f32_16x16x32_f16(a1h, bh, acc[1][ct], 0, 0, 0);
        }
    }

    const int orow = r0 + lk * 4;
#pragma unroll
    for (int rt = 0; rt < 2; ++rt) {
#pragma unroll
        for (int r = 0; r < 4; ++r) {
            int row = orow + rt * 16 + r;
            if (row < nrows) {
                float dd = dis[row];
#pragma unroll
                for (int ct = 0; ct < CT; ++ct) {
                    Y[(size_t)row * NOUT + ct * 16 + lrow] =
                        (_Float16)(dd * acc[rt][ct][r]);
                }
            }
        }
    }
}

template <int NOUT>
__global__ __launch_bounds__(256) void gemm_mfma(const _Float16* __restrict__ Xh,
                                                 const _Float16* __restrict__ WThi,
                                                 const _Float16* __restrict__ WTlo,
                                                 const float* __restrict__ dis,
                                                 _Float16* __restrict__ Y, int nrows) {
    gemm_core<NOUT, false>((const half8*)Xh, WThi, WTlo, dis, Y, nrows, nullptr);
}

// layer-1 variant: reads fp32 X directly, splits in-register (3-term, free)
__global__ __launch_bounds__(256) void gemm_mfma_l1(const float* __restrict__ X,
                                                    const _Float16* __restrict__ WThi,
                                                    const _Float16* __restrict__ WTlo,
                                                    const float* __restrict__ dis,
                                                    _Float16* __restrict__ Y, int nrows) {
    gemm_core<128, true>(nullptr, WThi, WTlo, dis, Y, nrows, (const float4*)X);
}

// ---------------------------------------------------------------------------
// agg helpers: accumulate 8 fp16 (one uint4) into a0..a7.
// Macro params prefixed to avoid colliding with vector member tokens (.w!).
// ---------------------------------------------------------------------------
#define ACC8(_v)                                                                    \
    do {                                                                            \
        float2 _f;                                                                  \
        _f = __half22float2(*reinterpret_cast<const __half2*>(&(_v).x));            \
        a0 += _f.x; a1 += _f.y;                                                     \
        _f = __half22float2(*reinterpret_cast<const __half2*>(&(_v).y));            \
        a2 += _f.x; a3 += _f.y;                                                     \
        _f = __half22float2(*reinterpret_cast<const __half2*>(&(_v).z));            \
        a4 += _f.x; a5 += _f.y;                                                     \
        _f = __half22float2(*reinterpret_cast<const __half2*>(&(_v).w));            \
        a6 += _f.x; a7 += _f.y;                                                     \
    } while (0)

#define ACC8W(_v, _scale)                                                           \
    do {                                                                            \
        float2 _f;                                                                  \
        _f = __half22float2(*reinterpret_cast<const __half2*>(&(_v).x));            \
        a0 = fmaf((_scale), _f.x, a0); a1 = fmaf((_scale), _f.y, a1);               \
        _f = __half22float2(*reinterpret_cast<const __half2*>(&(_v).y));            \
        a2 = fmaf((_scale), _f.x, a2); a3 = fmaf((_scale), _f.y, a3);               \
        _f = __half22float2(*reinterpret_cast<const __half2*>(&(_v).z));            \
        a4 = fmaf((_scale), _f.x, a4); a5 = fmaf((_scale), _f.y, a5);               \
        _f = __half22float2(*reinterpret_cast<const __half2*>(&(_v).w));            \
        a6 = fmaf((_scale), _f.x, a6); a7 = fmaf((_scale), _f.y, a7);               \
    } while (0)

// ---------------------------------------------------------------------------
// agg F=128: one wave/node; 16-lane group reads one 256B row (uint4/lane).
// 4 rows per gather instruction. Tail gather folds self-row.
// F16OUT: store plain fp16 (next GEMM input). else fp32.
// ---------------------------------------------------------------------------
template <bool RELU, bool F16OUT>
__global__ __launch_bounds__(256) void agg128_kernel(const __half* __restrict__ h,
                                                     const float* __restrict__ dis,
                                                     const int* __restrict__ offs,
                                                     const int* __restrict__ csr_s,
                                                     const float* __restrict__ bias,
                                                     float* __restrict__ outf,
                                                     __half* __restrict__ oh16, int n) {
    const int d = blockIdx.x * 4 + (threadIdx.x >> 6);
    if (d >= n) return;
    const int lane = threadIdx.x & 63;
    const int g = lane >> 4;     // row group 0..3
    const int p = lane & 15;     // uint4 position within the row
    const int beg = offs[d];
    const int end = offs[d + 1];
    const uint4* hv = (const uint4*)h;   // 16 uint4 per row

    float a0 = 0.f, a1 = 0.f, a2 = 0.f, a3 = 0.f;
    float a4 = 0.f, a5 = 0.f, a6 = 0.f, a7 = 0.f;

    int i = beg;
    for (; i + 16 <= end; i += 16) {     // 4 gathers (16 rows) in flight
        int r0 = csr_s[i + g];
        int r1 = csr_s[i + 4 + g];
        int r2 = csr_s[i + 8 + g];
        int r3 = csr_s[i + 12 + g];
        uint4 v0 = hv[(size_t)r0 * 16 + p];
        uint4 v1 = hv[(size_t)r1 * 16 + p];
        uint4 v2 = hv[(size_t)r2 * 16 + p];
        uint4 v3 = hv[(size_t)r3 * 16 + p];
        ACC8(v0); ACC8(v1); ACC8(v2); ACC8(v3);
    }
    if (i + 8 <= end) {
        int r0 = csr_s[i + g];
        int r1 = csr_s[i + 4 + g];
        uint4 v0 = hv[(size_t)r0 * 16 + p];
        uint4 v1 = hv[(size_t)r1 * 16 + p];
        ACC8(v0); ACC8(v1);
        i += 8;
    }
    if (i + 4 <= end) {
        int r0 = csr_s[i + g];
        uint4 v0 = hv[(size_t)r0 * 16 + p];
        ACC8(v0);
        i += 4;
    }
    {   // tail: m in [0,3] residual edges; group m = self row; groups>m zero
        int m = end - i;
        int row = (g < m) ? csr_s[i + g] : d;
        float wt = (g <= m) ? 1.f : 0.f;
        uint4 v = hv[(size_t)row * 16 + p];
        ACC8W(v, wt);
    }

    a0 += __shfl_xor(a0, 16); a0 += __shfl_xor(a0, 32);
    a1 += __shfl_xor(a1, 16); a1 += __shfl_xor(a1, 32);
    a2 += __shfl_xor(a2, 16); a2 += __shfl_xor(a2, 32);
    a3 += __shfl_xor(a3, 16); a3 += __shfl_xor(a3, 32);
    a4 += __shfl_xor(a4, 16); a4 += __shfl_xor(a4, 32);
    a5 += __shfl_xor(a5, 16); a5 += __shfl_xor(a5, 32);
    a6 += __shfl_xor(a6, 16); a6 += __shfl_xor(a6, 32);
    a7 += __shfl_xor(a7, 16); a7 += __shfl_xor(a7, 32);

    if (lane < 16) {   // lanes 0..15 own feats 8p..8p+7
        float dd = dis[d];
        float4 b0 = ((const float4*)bias)[2 * p];
        float4 b1 = ((const float4*)bias)[2 * p + 1];
        float r0 = fmaf(dd, a0, b0.x);
        float r1 = fmaf(dd, a1, b0.y);
        float r2 = fmaf(dd, a2, b0.z);
        float r3 = fmaf(dd, a3, b0.w);
        float r4 = fmaf(dd, a4, b1.x);
        float r5 = fmaf(dd, a5, b1.y);
        float r6 = fmaf(dd, a6, b1.z);
        float r7 = fmaf(dd, a7, b1.w);
        if (RELU) {
            r0 = fmaxf(r0, 0.f); r1 = fmaxf(r1, 0.f);
            r2 = fmaxf(r2, 0.f); r3 = fmaxf(r3, 0.f);
            r4 = fmaxf(r4, 0.f); r5 = fmaxf(r5, 0.f);
            r6 = fmaxf(r6, 0.f); r7 = fmaxf(r7, 0.f);
        }
        if constexpr (F16OUT) {
            __half2 q0 = __halves2half2(__float2half(r0), __float2half(r1));
            __half2 q1 = __halves2half2(__float2half(r2), __float2half(r3));
            __half2 q2 = __halves2half2(__float2half(r4), __float2half(r5));
            __half2 q3 = __halves2half2(__float2half(r6), __float2half(r7));
            uint4 uh;
            uh.x = *reinterpret_cast<unsigned*>(&q0);
            uh.y = *reinterpret_cast<unsigned*>(&q1);
            uh.z = *reinterpret_cast<unsigned*>(&q2);
            uh.w = *reinterpret_cast<unsigned*>(&q3);
            ((uint4*)oh16)[(size_t)d * 16 + p] = uh;
        } else {
            ((float4*)outf)[(size_t)d * 32 + 2 * p] = make_float4(r0, r1, r2, r3);
            ((float4*)outf)[(size_t)d * 32 + 2 * p + 1] = make_float4(r4, r5, r6, r7);
        }
    }
}

// ---------------------------------------------------------------------------
// agg F=64 (final layer, fp32 out): 8-lane group reads one 128B row
// (uint4/lane). 8 rows per gather instruction. Same tail trick (m in [0,7]).
// ---------------------------------------------------------------------------
__global__ __launch_bounds__(256) void agg64_kernel(const __half* __restrict__ h,
                                                    const float* __restrict__ dis,
                                                    const int* __restrict__ offs,
                                                    const int* __restrict__ csr_s,
                                                    const float* __restrict__ bias,
                                                    float* __restrict__ outf, int n) {
    const int d = blockIdx.x * 4 + (threadIdx.x >> 6);
    if (d >= n) return;
    const int lane = threadIdx.x & 63;
    const int g = lane >> 3;     // row group 0..7
    const int p = lane & 7;      // uint4 position within the row
    const int beg = offs[d];
    const int end = offs[d + 1];
    const uint4* hv = (const uint4*)h;   // 8 uint4 per row

    float a0 = 0.f, a1 = 0.f, a2 = 0.f, a3 = 0.f;
    float a4 = 0.f, a5 = 0.f, a6 = 0.f, a7 = 0.f;

    int i = beg;
    for (; i + 16 <= end; i += 16) {     // 2 gathers (16 rows) in flight
        int r0 = csr_s[i + g];
        int r1 = csr_s[i + 8 + g];
        uint4 v0 = hv[(size_t)r0 * 8 + p];
        uint4 v1 = hv[(size_t)r1 * 8 + p];
        ACC8(v0); ACC8(v1);
    }
    if (i + 8 <= end) {
        int r0 = csr_s[i + g];
        uint4 v0 = hv[(size_t)r0 * 8 + p];
        ACC8(v0);
        i += 8;
    }
    {   // tail: m in [0,7]; group m = self row; groups>m zero
        int m = end - i;
        int row = (g < m) ? csr_s[i + g] : d;
        float wt = (g <= m) ? 1.f : 0.f;
        uint4 v = hv[(size_t)row * 8 + p];
        ACC8W(v, wt);
    }

    a0 += __shfl_xor(a0, 8); a0 += __shfl_xor(a0, 16); a0 += __shfl_xor(a0, 32);
    a1 += __shfl_xor(a1, 8); a1 += __shfl_xor(a1, 16); a1 += __shfl_xor(a1, 32);
    a2 += __shfl_xor(a2, 8); a2 += __shfl_xor(a2, 16); a2 += __shfl_xor(a2, 32);
    a3 += __shfl_xor(a3, 8); a3 += __shfl_xor(a3, 16); a3 += __shfl_xor(a3, 32);
    a4 += __shfl_xor(a4, 8); a4 += __shfl_xor(a4, 16); a4 += __shfl_xor(a4, 32);
    a5 += __shfl_xor(a5, 8); a5 += __shfl_xor(a5, 16); a5 += __shfl_xor(a5, 32);
    a6 += __shfl_xor(a6, 8); a6 += __shfl_xor(a6, 16); a6 += __shfl_xor(a6, 32);
    a7 += __shfl_xor(a7, 8); a7 += __shfl_xor(a7, 16); a7 += __shfl_xor(a7, 32);

    if (lane < 8) {   // lanes 0..7 own feats 8p..8p+7
        float dd = dis[d];
        float4 b0 = ((const float4*)bias)[2 * p];
        float4 b1 = ((const float4*)bias)[2 * p + 1];
        float r0 = fmaf(dd, a0, b0.x);
        float r1 = fmaf(dd, a1, b0.y);
        float r2 = fmaf(dd, a2, b0.z);
        float r3 = fmaf(dd, a3, b0.w);
        float r4 = fmaf(dd, a4, b1.x);
        float r5 = fmaf(dd, a5, b1.y);
        float r6 = fmaf(dd, a6, b1.z);
        float r7 = fmaf(dd, a7, b1.w);
        ((float4*)outf)[(size_t)d * 16 + 2 * p] = make_float4(r0, r1, r2, r3);
        ((float4*)outf)[(size_t)d * 16 + 2 * p + 1] = make_float4(r4, r5, r6, r7);
    }
}

// ---------------------------------------------------------------------------

extern "C" void kernel_launch(void* const* d_in, const int* in_sizes, int n_in,
                              void* d_out, int out_size, void* d_ws, size_t ws_size,
                              hipStream_t stream) {
    const float* x  = (const float*)d_in[0];
    const int*   ei = (const int*)d_in[1];
    const float* W1 = (const float*)d_in[2];
    const float* b1 = (const float*)d_in[3];
    const float* W2 = (const float*)d_in[4];
    const float* b2 = (const float*)d_in[5];
    const float* W3 = (const float*)d_in[6];
    const float* b3 = (const float*)d_in[7];

    const int N = in_sizes[0] / 128;
    const int E = in_sizes[1] / 2;
    const int* src = ei;
    const int* dst = ei + E;
    float* out = (float*)d_out;

    char* w = (char*)d_ws;
    auto take = [&](size_t bytes) -> void* {
        void* p = (void*)w;
        w += (bytes + 255) & ~(size_t)255;
        return p;
    };
    int*      counts = (int*)take((size_t)N * 4);
    int*      offs   = (int*)take((size_t)(N + 1) * 4);
    float*    dis    = (float*)take((size_t)N * 4);
    int*      bsum   = (int*)take((size_t)1024 * 4);
    int*      csr_s  = (int*)take((size_t)E * 4);
    _Float16* G16    = (_Float16*)take((size_t)N * 128 * 2);  // prescaled fp16 rows
    _Float16* H16    = (_Float16*)take((size_t)N * 128 * 2);  // fp16 inter-layer H
    _Float16* Whi    = (_Float16*)take((size_t)40960 * 2);
    _Float16* Wlo    = (_Float16*)take((size_t)40960 * 2);
    // rank is only live between count_kernel and fill_kernel; G16 is only
    // written from the first GEMM onward (same stream => sequential). Alias.
    int*      rank   = (int*)G16;

    const int NBLK = (N + 256) / 256;

    // --- graph preprocessing ---
    hipMemsetAsync(counts, 0, (size_t)N * 4, stream);
    count_kernel<<<2048, 256, 0, stream>>>(dst, counts, rank, E);
    block_sum_kernel<<<NBLK, 256, 0, stream>>>(counts, bsum, N);
    small_scan_kernel<<<1, 256, 0, stream>>>(bsum, NBLK);
    scan_block_kernel<<<NBLK, 256, 0, stream>>>(counts, bsum, offs, dis, N, E);
    fill_kernel<<<2048, 256, 0, stream>>>(src, dst, offs, rank, csr_s, E);

    // --- weight split (160 KB, trivial) ---
    wsplit_kernel<<<160, 256, 0, stream>>>(W1, W2, W3, Whi, Wlo);

    const int gblocks = (N + 127) / 128;   // 128 rows per block (4 waves x 32)
    const int ablocks = (N + 3) / 4;

    // layer 1 (fp32 X split in-register, 3-term)
    gemm_mfma_l1<<<gblocks, 256, 0, stream>>>(x, Whi, Wlo, dis, G16, N);
    agg128_kernel<true, true><<<ablocks, 256, 0, stream>>>(
        (const __half*)G16, dis, offs, csr_s, b1, nullptr, (__half*)H16, N);
    // layer 2 (fp16 H, 2-term)
    gemm_mfma<128><<<gblocks, 256, 0, stream>>>(H16, Whi + 16384, Wlo + 16384,
                                                dis, G16, N);
    agg128_kernel<true, true><<<ablocks, 256, 0, stream>>>(
        (const __half*)G16, dis, offs, csr_s, b2, nullptr, (__half*)H16, N);
    // layer 3 (fp16 H, 2-term)
    gemm_mfma<64><<<gblocks, 256, 0, stream>>>(H16, Whi + 32768, Wlo + 32768,
                                               dis, G16, N);
    agg64_kernel<<<ablocks, 256, 0, stream>>>((const __half*)G16, dis, offs, csr_s,
                                              b3, out, N);
}